// Round 1
// baseline (23799.849 us; speedup 1.0000x reference)
//
#include <hip/hip_runtime.h>
#include <math.h>

// ---------------------------------------------------------------------------
// TensorProcessor: conv3d(1,3,1)+bias+relu -> Tucker-HOOI core (8,6,6,6)
// Round 1: full fp32 pipeline; eigh = LAPACK-convention Householder tridiag
// + Sturm bisection (top-r) + inverse iteration + back-transform, with
// CANONICAL eigenvector signs (max-|component| positive). This will likely
// mismatch LAPACK syevd signs -> expect absmax ~ 2x|core entry|. The tridiag
// infrastructure is the foundation for a LAPACK-sign-faithful solver in R2+.
// ---------------------------------------------------------------------------

// tensor t: (32,100,128,64) = 26,214,400 floats
// ws layout (float offsets)
constexpr long long OFF_T   = 0LL;          // 26,214,400
constexpr long long OFF_A   = 26214400LL;   // tmpA 6,553,600
constexpr long long OFF_B   = 32768000LL;   // tmpB 1,572,864
constexpr long long OFF_G   = 34340864LL;   // 16,384
constexpr long long OFF_F0  = 34357248LL;   // 32*8
constexpr long long OFF_F1  = 34357504LL;   // 100*6
constexpr long long OFF_F2  = 34358104LL;   // 128*6
constexpr long long OFF_F3  = 34358872LL;   // 64*6
constexpr long long OFF_VHH = 34359256LL;   // 16,384 (householder vectors)
constexpr long long OFF_TAU = 34375640LL;   // 128
constexpr long long OFF_PART= OFF_A;        // 120*16384 aliases tmpA (init only)

// ---------------- conv + relu ----------------
__global__ void kconv(const float* __restrict__ x, const float* __restrict__ cw,
                      const float* __restrict__ cb, float* __restrict__ t) {
  int idx = blockIdx.x * blockDim.x + threadIdx.x;
  if (idx >= 26214400) return;
  int w  = idx & 63;
  int h  = (idx >> 6) & 127;
  int d  = (idx >> 13) % 100;
  int o  = idx / 819200;
  float acc = cb[o];
#pragma unroll
  for (int i = 0; i < 4; ++i) {
    const float* xi = x + (((long long)i * 100 + d) * 130 + h) * 64 + w;
#pragma unroll
    for (int kh = 0; kh < 3; ++kh)
      acc = fmaf(cw[(o * 4 + i) * 3 + kh], xi[kh * 64], acc);
  }
  t[idx] = fmaxf(acc, 0.f);
}

// ---------------- big gram (init HOSVD): G = X X^T over fibers ----------------
// T viewed as (P, D, Q); fiber f=(p,q); addr(a,f) = (p*D+a)*Q + q
template<int D, bool TRANS>
__global__ void kgram_big(const float* __restrict__ T, float* __restrict__ part,
                          int P, long long Q) {
  constexpr int C = 64;
  constexpr int SUB = (D + 63) / 64;
  constexpr int DP = SUB * 64;
  __shared__ float tile[DP * (C + 1)];
  const int tid = threadIdx.x;                 // 256
  const int ta = tid >> 4, tb = tid & 15;
  float acc[SUB][SUB][4][4];
#pragma unroll
  for (int a = 0; a < SUB; ++a)
#pragma unroll
    for (int b = 0; b < SUB; ++b)
#pragma unroll
      for (int i = 0; i < 4; ++i)
#pragma unroll
        for (int j = 0; j < 4; ++j) acc[a][b][i][j] = 0.f;

  const long long nfib = (long long)P * Q;
  const int nchunk = (int)(nfib / C);
  for (int ch = blockIdx.x; ch < nchunk; ch += gridDim.x) {
    const long long base = (long long)ch * C;
    __syncthreads();
    if (TRANS) {
      // Q==1, D==64: contiguous load, transpose into LDS
      for (int e = tid; e < D * C; e += 256) {
        int a = e & 63, cc = e >> 6;
        tile[a * (C + 1) + cc] = T[base * D + e];
      }
    } else {
      for (int e = tid; e < DP * C; e += 256) {
        int a = e / C, cc = e % C;
        float v = 0.f;
        if (a < D) {
          long long f = base + cc;
          long long p = f / Q, q = f - p * Q;
          v = T[(p * D + a) * Q + q];
        }
        tile[a * (C + 1) + cc] = v;
      }
    }
    __syncthreads();
    for (int cc = 0; cc < C; ++cc) {
      float av[SUB][4], bv[SUB][4];
#pragma unroll
      for (int si = 0; si < SUB; ++si)
#pragma unroll
        for (int i = 0; i < 4; ++i) av[si][i] = tile[(si * 64 + ta * 4 + i) * (C + 1) + cc];
#pragma unroll
      for (int sj = 0; sj < SUB; ++sj)
#pragma unroll
        for (int j = 0; j < 4; ++j) bv[sj][j] = tile[(sj * 64 + tb * 4 + j) * (C + 1) + cc];
#pragma unroll
      for (int si = 0; si < SUB; ++si)
#pragma unroll
        for (int sj = 0; sj < SUB; ++sj)
#pragma unroll
          for (int i = 0; i < 4; ++i)
#pragma unroll
            for (int j = 0; j < 4; ++j)
              acc[si][sj][i][j] = fmaf(av[si][i], bv[sj][j], acc[si][sj][i][j]);
    }
  }
  float* pb = part + (long long)blockIdx.x * D * D;
  for (int si = 0; si < SUB; ++si)
    for (int i = 0; i < 4; ++i) {
      int a = si * 64 + ta * 4 + i;
      if (a >= D) continue;
      for (int sj = 0; sj < SUB; ++sj)
        for (int j = 0; j < 4; ++j) {
          int b = sj * 64 + tb * 4 + j;
          if (b >= D) continue;
          pb[a * D + b] = acc[si][sj][i][j];
        }
    }
}

__global__ void kreduce(const float* __restrict__ part, float* __restrict__ G, int DD) {
  int i = blockIdx.x * blockDim.x + threadIdx.x;
  if (i >= DD) return;
  float s = 0.f;
  for (int b = 0; b < 120; ++b) s += part[(long long)b * DD + i];
  G[i] = s;
}

// ---------------- small gram (projected Y) ----------------
__global__ void kgram_small(const float* __restrict__ Y, float* __restrict__ G,
                            int P, int d, int Q) {
  int pair = blockIdx.x * blockDim.x + threadIdx.x;
  if (pair >= d * d) return;
  int a = pair / d, b = pair % d;
  float s = 0.f;
  for (int p = 0; p < P; ++p) {
    const float* ya = Y + ((long long)p * d + a) * Q;
    const float* yb = Y + ((long long)p * d + b) * Q;
    for (int q = 0; q < Q; ++q) s = fmaf(ya[q], yb[q], s);
  }
  G[pair] = s;
}

// ---------------- mode contraction: out[p,j,q] = sum_a F[a,j] in[p,a,q] ----------------
template<int R>
__global__ void kcontract(const float* __restrict__ in, const float* __restrict__ F,
                          float* __restrict__ out, int P, int d, long long Q) {
  long long total = (long long)P * Q;
  long long idx = (long long)blockIdx.x * blockDim.x + threadIdx.x;
  if (idx >= total) return;
  long long p = idx / Q, q = idx - p * Q;
  float acc[R];
#pragma unroll
  for (int j = 0; j < R; ++j) acc[j] = 0.f;
  const float* ip = in + (p * d) * Q + q;
  for (int a = 0; a < d; ++a) {
    float v = ip[(long long)a * Q];
#pragma unroll
    for (int j = 0; j < R; ++j) acc[j] = fmaf(F[a * R + j], v, acc[j]);
  }
  float* op = out + (p * R) * Q + q;
#pragma unroll
  for (int j = 0; j < R; ++j) op[(long long)j * Q] = acc[j];
}

// ---------------- eigh: top-r eigenvectors of symmetric G (n<=128) ----------------
#define EIG_THREADS 512

__device__ __forceinline__ int pidx(int i, int j, int n) {
  if (i > j) { int t = i; i = j; j = t; }
  return i * n - ((i * (i - 1)) >> 1) + (j - i);
}

__device__ __forceinline__ float blkReduceSum(float v, volatile float* red, int tid) {
  __syncthreads();
#pragma unroll
  for (int off = 32; off > 0; off >>= 1) v += __shfl_down(v, off, 64);
  if ((tid & 63) == 0) red[tid >> 6] = v;
  __syncthreads();
  float s = 0.f;
#pragma unroll
  for (int w = 0; w < EIG_THREADS / 64; ++w) s += red[w];
  return s;
}

__global__ __launch_bounds__(EIG_THREADS)
void keigh(const float* __restrict__ G, float* __restrict__ F,
           float* __restrict__ Vhh, float* __restrict__ tauG,
           int n, int r) {
  __shared__ float Apk[8256];
  __shared__ float dd[128], ee[128];
  __shared__ float uu[128], ww[128];
  __shared__ float vt[8][128];
  __shared__ float slv[8][384];       // u0,u1,u2 bands per vector
  __shared__ float lam[8];
  __shared__ float red[8];
  __shared__ float sca[4];
  const int tid = threadIdx.x;
  const int lane = tid & 63, wv = tid >> 6;

  // load packed upper
  for (int t = tid; t < n * n; t += EIG_THREADS) {
    int i = t / n, j = t % n;
    if (i <= j) Apk[pidx(i, j, n)] = G[t];
  }
  __syncthreads();

  // ---- Householder tridiagonalization (LAPACK ssytd2 'L' conventions) ----
  for (int i = 0; i <= n - 3; ++i) {
    float prt = 0.f;
    for (int k = i + 2 + tid; k < n; k += EIG_THREADS) {
      float v = Apk[pidx(k, i, n)];
      prt += v * v;
    }
    float xnorm2 = blkReduceSum(prt, red, tid);
    float alpha = Apk[pidx(i + 1, i, n)];
    float beta, tau_i, scl;
    if (xnorm2 == 0.f) { beta = alpha; tau_i = 0.f; scl = 0.f; }
    else {
      float an = sqrtf(alpha * alpha + xnorm2);
      beta = (alpha >= 0.f) ? -an : an;           // slarfg: beta = -sign(alpha)*norm
      tau_i = (beta - alpha) / beta;
      scl = 1.f / (alpha - beta);
    }
    for (int k = tid; k < n; k += EIG_THREADS) {
      float u = 0.f;
      if (k == i + 1) u = 1.f;
      else if (k >= i + 2) u = Apk[pidx(k, i, n)] * scl;
      uu[k] = u;
    }
    __syncthreads();
    // p = tau * A_sub * u
    for (int k = i + 1 + tid; k < n; k += EIG_THREADS) {
      float s = 0.f;
      for (int l = i + 1; l < n; ++l) s = fmaf(Apk[pidx(k, l, n)], uu[l], s);
      ww[k] = tau_i * s;
    }
    __syncthreads();
    float p2 = 0.f;
    for (int k = i + 1 + tid; k < n; k += EIG_THREADS) p2 += ww[k] * uu[k];
    float pu = blkReduceSum(p2, red, tid);
    float halfc = -0.5f * tau_i * pu;
    for (int k = i + 1 + tid; k < n; k += EIG_THREADS) ww[k] += halfc * uu[k];
    __syncthreads();
    // A -= u w^T + w u^T (trailing, packed)
    const int mm = n - 1 - i;
    for (int t2 = tid; t2 < mm * mm; t2 += EIG_THREADS) {
      int k = i + 1 + t2 / mm, l = i + 1 + t2 % mm;
      if (k <= l) Apk[pidx(k, l, n)] -= uu[k] * ww[l] + ww[k] * uu[l];
    }
    if (tid == 0) { ee[i] = beta; tauG[i] = tau_i; }
    for (int k = tid; k < n; k += EIG_THREADS) Vhh[i * n + k] = uu[k];
    __syncthreads();
  }
  for (int k = tid; k < n; k += EIG_THREADS) dd[k] = Apk[pidx(k, k, n)];
  if (tid == 0) ee[n - 2] = Apk[pidx(n - 1, n - 2, n)];
  __syncthreads();

  // ---- Gershgorin bounds + pivmin ----
  if (tid == 0) {
    float lo = 3.4e38f, hi = -3.4e38f, me2 = 0.f;
    for (int i = 0; i < n; ++i) {
      float rad = 0.f;
      if (i > 0) rad += fabsf(ee[i - 1]);
      if (i < n - 1) { rad += fabsf(ee[i]); me2 = fmaxf(me2, ee[i] * ee[i]); }
      lo = fminf(lo, dd[i] - rad);
      hi = fmaxf(hi, dd[i] + rad);
    }
    float span = hi - lo;
    sca[0] = lo - 0.001f * span - 1e-20f;
    sca[1] = hi + 0.001f * span + 1e-20f;
    sca[2] = 1.1754944e-38f * fmaxf(1.f, me2);
  }
  __syncthreads();
  const float pivmin = sca[2];

  // ---- Sturm bisection for top-r eigenvalues ----
  if (tid < r) {
    int krank = n - 1 - tid;   // 0-indexed ascending rank
    float lo = sca[0], hi = sca[1];
    for (int it = 0; it < 40; ++it) {
      float mid = 0.5f * (lo + hi);
      int cnt = 0;
      float q = dd[0] - mid;
      if (q < 0.f) cnt++;
      for (int i = 1; i < n; ++i) {
        if (fabsf(q) < pivmin) q = -pivmin;
        q = dd[i] - mid - ee[i - 1] * ee[i - 1] / q;
        if (q < 0.f) cnt++;
      }
      if (cnt > krank) hi = mid; else lo = mid;
    }
    lam[tid] = 0.5f * (lo + hi) * (1.f + (float)tid * 3e-7f);
  }
  __syncthreads();

  // ---- inverse iteration on tridiagonal (one thread per vector) ----
  if (tid < r) {
    const int j = tid;
    float* u0 = &slv[j][0];
    float* u1 = &slv[j][128];
    float* u2 = &slv[j][256];
    float* v = &vt[j][0];
    const float lj = lam[j];
    for (int k = 0; k < n; ++k) v[k] = 1.f;
    for (int itr = 0; itr < 3; ++itr) {
      for (int i = 0; i < n; ++i) {
        u0[i] = dd[i] - lj;
        u1[i] = (i < n - 1) ? ee[i] : 0.f;
        u2[i] = 0.f;
      }
      for (int i = 0; i < n - 1; ++i) {
        float bi = ee[i];
        float ai = u0[i];
        if (fabsf(ai) >= fabsf(bi)) {
          if (fabsf(ai) < pivmin) ai = (ai >= 0.f ? pivmin : -pivmin);
          float m = bi / ai;
          u0[i] = ai;
          u0[i + 1] -= m * u1[i];
          v[i + 1] -= m * v[i];
        } else {
          float m = ai / bi;                // |m| <= 1
          float ci = u1[i];
          float d1 = u0[i + 1], e1 = u1[i + 1];
          u0[i] = bi; u1[i] = d1; u2[i] = e1;
          u0[i + 1] = ci - m * d1;
          u1[i + 1] = -m * e1;
          float tv = v[i];
          v[i] = v[i + 1];
          v[i + 1] = tv - m * v[i];
        }
      }
      if (fabsf(u0[n - 1]) < pivmin) u0[n - 1] = (u0[n - 1] >= 0.f ? pivmin : -pivmin);
      v[n - 1] = v[n - 1] / u0[n - 1];
      v[n - 2] = (v[n - 2] - u1[n - 2] * v[n - 1]) / u0[n - 2];
      for (int i = n - 3; i >= 0; --i)
        v[i] = (v[i] - u1[i] * v[i + 1] - u2[i] * v[i + 2]) / u0[i];
      float mx = 0.f;
      for (int k = 0; k < n; ++k) mx = fmaxf(mx, fabsf(v[k]));
      float inv = 1.f / fmaxf(mx, 1e-30f);
      for (int k = 0; k < n; ++k) v[k] *= inv;
    }
  }
  __syncthreads();

  // ---- MGS orthonormalization (block-parallel) ----
  for (int j = 0; j < r; ++j) {
    for (int i = 0; i < j; ++i) {
      float p_ = 0.f;
      for (int k = tid; k < n; k += EIG_THREADS) p_ += vt[i][k] * vt[j][k];
      float dp = blkReduceSum(p_, red, tid);
      for (int k = tid; k < n; k += EIG_THREADS) vt[j][k] -= dp * vt[i][k];
    }
    float p_ = 0.f;
    for (int k = tid; k < n; k += EIG_THREADS) p_ += vt[j][k] * vt[j][k];
    float nn = blkReduceSum(p_, red, tid);
    float inv = rsqrtf(fmaxf(nn, 1e-33f));
    for (int k = tid; k < n; k += EIG_THREADS) vt[j][k] *= inv;
    __syncthreads();
  }

  // ---- back-transform: v = H_0 ... H_{n-3} v (one wave per vector) ----
  if (wv < r) {
    float* v = &vt[wv][0];
    for (int h = n - 3; h >= 0; --h) {
      float dp = 0.f;
      for (int k = lane; k < n; k += 64) dp += Vhh[h * n + k] * v[k];
#pragma unroll
      for (int off = 32; off > 0; off >>= 1) dp += __shfl_down(dp, off, 64);
      dp = __shfl(dp, 0, 64);
      float c = tauG[h] * dp;
      for (int k = lane; k < n; k += 64) v[k] -= c * Vhh[h * n + k];
    }
  }
  __syncthreads();

  // ---- canonical sign (max-|component| positive) + write F (n x r) ----
  if (wv < r) {
    float* v = &vt[wv][0];
    float ma = -1.f; int mi = 0x7fffffff;
    for (int k = lane; k < n; k += 64) {
      float a = fabsf(v[k]);
      if (a > ma || (a == ma && k < mi)) { ma = a; mi = k; }
    }
#pragma unroll
    for (int off = 32; off > 0; off >>= 1) {
      float oa = __shfl_down(ma, off, 64);
      int oi = __shfl_down(mi, off, 64);
      if (oa > ma || (oa == ma && oi < mi)) { ma = oa; mi = oi; }
    }
    mi = __shfl(mi, 0, 64);
    float sg = (v[mi] < 0.f) ? -1.f : 1.f;
    for (int k = lane; k < n; k += 64) F[k * r + wv] = sg * v[k];
  }
}

// ---------------------------------------------------------------------------
extern "C" void kernel_launch(void* const* d_in, const int* in_sizes, int n_in,
                              void* d_out, int out_size, void* d_ws, size_t ws_size,
                              hipStream_t stream) {
  (void)in_sizes; (void)n_in; (void)out_size; (void)ws_size;
  const float* x  = (const float*)d_in[0];
  const float* cw = (const float*)d_in[1];
  const float* cb = (const float*)d_in[2];
  float* out = (float*)d_out;
  float* ws  = (float*)d_ws;

  float* T    = ws + OFF_T;
  float* TA   = ws + OFF_A;
  float* TB   = ws + OFF_B;
  float* G    = ws + OFF_G;
  float* F0   = ws + OFF_F0;
  float* F1   = ws + OFF_F1;
  float* F2   = ws + OFF_F2;
  float* F3   = ws + OFF_F3;
  float* Vhh  = ws + OFF_VHH;
  float* tau  = ws + OFF_TAU;
  float* PART = ws + OFF_PART;

  kconv<<<(26214400 + 255) / 256, 256, 0, stream>>>(x, cw, cb, T);

  // ---- HOSVD init ----
  kgram_big<32, false><<<120, 256, 0, stream>>>(T, PART, 1, 819200);
  kreduce<<<(1024 + 255) / 256, 256, 0, stream>>>(PART, G, 1024);
  keigh<<<1, EIG_THREADS, 0, stream>>>(G, F0, Vhh, tau, 32, 8);

  kgram_big<100, false><<<120, 256, 0, stream>>>(T, PART, 32, 8192);
  kreduce<<<(10000 + 255) / 256, 256, 0, stream>>>(PART, G, 10000);
  keigh<<<1, EIG_THREADS, 0, stream>>>(G, F1, Vhh, tau, 100, 6);

  kgram_big<128, false><<<120, 256, 0, stream>>>(T, PART, 3200, 64);
  kreduce<<<(16384 + 255) / 256, 256, 0, stream>>>(PART, G, 16384);
  keigh<<<1, EIG_THREADS, 0, stream>>>(G, F2, Vhh, tau, 128, 6);

  kgram_big<64, true><<<120, 256, 0, stream>>>(T, PART, 409600, 1);
  kreduce<<<(4096 + 255) / 256, 256, 0, stream>>>(PART, G, 4096);
  keigh<<<1, EIG_THREADS, 0, stream>>>(G, F3, Vhh, tau, 64, 6);

  // ---- HOOI sweeps ----
  for (int sweep = 0; sweep < 5; ++sweep) {
    // m = 0: project modes 1,2,3 -> Y (32,6,6,6)
    kcontract<6><<<(262144 + 255) / 256, 256, 0, stream>>>(T, F1, TA, 32, 100, 8192);
    kcontract<6><<<(12288 + 255) / 256, 256, 0, stream>>>(TA, F2, TB, 192, 128, 64);
    kcontract<6><<<(1152 + 255) / 256, 256, 0, stream>>>(TB, F3, TA, 1152, 64, 1);
    kgram_small<<<(1024 + 255) / 256, 256, 0, stream>>>(TA, G, 1, 32, 216);
    keigh<<<1, EIG_THREADS, 0, stream>>>(G, F0, Vhh, tau, 32, 8);
    // m = 1: Y (8,100,6,6)
    kcontract<8><<<(819200 + 255) / 256, 256, 0, stream>>>(T, F0, TA, 1, 32, 819200);
    kcontract<6><<<(51200 + 255) / 256, 256, 0, stream>>>(TA, F2, TB, 800, 128, 64);
    kcontract<6><<<(4800 + 255) / 256, 256, 0, stream>>>(TB, F3, TA, 4800, 64, 1);
    kgram_small<<<(10000 + 255) / 256, 256, 0, stream>>>(TA, G, 8, 100, 36);
    keigh<<<1, EIG_THREADS, 0, stream>>>(G, F1, Vhh, tau, 100, 6);
    // m = 2: Y (8,6,128,6)
    kcontract<8><<<(819200 + 255) / 256, 256, 0, stream>>>(T, F0, TA, 1, 32, 819200);
    kcontract<6><<<(65536 + 255) / 256, 256, 0, stream>>>(TA, F1, TB, 8, 100, 8192);
    kcontract<6><<<(6144 + 255) / 256, 256, 0, stream>>>(TB, F3, TA, 6144, 64, 1);
    kgram_small<<<(16384 + 255) / 256, 256, 0, stream>>>(TA, G, 48, 128, 6);
    keigh<<<1, EIG_THREADS, 0, stream>>>(G, F2, Vhh, tau, 128, 6);
    // m = 3: Y (8,6,6,64)
    kcontract<8><<<(819200 + 255) / 256, 256, 0, stream>>>(T, F0, TA, 1, 32, 819200);
    kcontract<6><<<(65536 + 255) / 256, 256, 0, stream>>>(TA, F1, TB, 8, 100, 8192);
    kcontract<6><<<(3072 + 255) / 256, 256, 0, stream>>>(TB, F2, TA, 48, 128, 64);
    kgram_small<<<(4096 + 255) / 256, 256, 0, stream>>>(TA, G, 288, 64, 1);
    keigh<<<1, EIG_THREADS, 0, stream>>>(G, F3, Vhh, tau, 64, 6);
  }

  // ---- core = t x0 F0^T x1 F1^T x2 F2^T x3 F3^T -> (8,6,6,6) ----
  kcontract<8><<<(819200 + 255) / 256, 256, 0, stream>>>(T, F0, TA, 1, 32, 819200);
  kcontract<6><<<(65536 + 255) / 256, 256, 0, stream>>>(TA, F1, TB, 8, 100, 8192);
  kcontract<6><<<(3072 + 255) / 256, 256, 0, stream>>>(TB, F2, TA, 48, 128, 64);
  kcontract<6><<<(288 + 255) / 256, 256, 0, stream>>>(TA, F3, out, 288, 64, 1);
}

// Round 2
// 22178.662 us; speedup vs baseline: 1.0731x; 1.0731x over previous
//
#include <hip/hip_runtime.h>
#include <math.h>

// ---------------------------------------------------------------------------
// TensorProcessor: conv3d(1,3,1)+bias+relu -> Tucker-HOOI core (8,6,6,6)
// Round 2: same arithmetic as round 1 (passed, absmax 12.375), restructured
// for latency: triangular trailing update (no int-div, no wasted half),
// incremental-index matvec, register-carry inverse iteration, padded LDS,
// batched init eighs, cached TC = T x0 F0^T per sweep.
// ---------------------------------------------------------------------------

// ws layout (float offsets) -- stays within round-1 footprint (~137.5 MB)
constexpr long long OFF_T   = 0LL;                 // 26,214,400
constexpr long long OFF_TC  = 26214400LL;          // 6,553,600
constexpr long long OFF_TB  = 32768000LL;          // 1,572,864
constexpr long long OFF_PART= OFF_TC;              // 120*16384 (init only)
constexpr long long OFF_TD0a= OFF_TC;              // mode0 (32,6,6,64)=73,728
constexpr long long OFF_TD0b= OFF_TC + 131072;     // mode0 (32,6,6,6)=6,912
constexpr long long OFF_VH0 = OFF_TC;              // init Vhh: 4*16384 (alias PART, post-consumption)
constexpr long long OFF_TA0 = OFF_TC + 65536;      // init tau: 4*128
constexpr long long OFF_TD  = OFF_TB + 1000000LL;  // sweep small tensors <=36,864
constexpr long long OFF_G0  = OFF_TB + 1400000LL;  // 1,024
constexpr long long OFF_G1  = OFF_G0 + 1024;       // 10,000
constexpr long long OFF_G2  = OFF_G1 + 10000;      // 16,384
constexpr long long OFF_G3  = OFF_G2 + 16384;      // 4,096  (ends < TB end)
constexpr long long OFF_F0  = 34340864LL;          // 256
constexpr long long OFF_F1  = OFF_F0 + 256;        // 600
constexpr long long OFF_F2  = OFF_F1 + 600;        // 768
constexpr long long OFF_F3  = OFF_F2 + 768;        // 384
constexpr long long OFF_VHS = 34342912LL;          // 16,384 (sweep Vhh)
constexpr long long OFF_TAS = OFF_VHS + 16384;     // 128

// ---------------- conv + relu ----------------
__global__ void kconv(const float* __restrict__ x, const float* __restrict__ cw,
                      const float* __restrict__ cb, float* __restrict__ t) {
  int idx = blockIdx.x * blockDim.x + threadIdx.x;
  if (idx >= 26214400) return;
  int w  = idx & 63;
  int h  = (idx >> 6) & 127;
  int d  = (idx >> 13) % 100;
  int o  = idx / 819200;
  float acc = cb[o];
#pragma unroll
  for (int i = 0; i < 4; ++i) {
    const float* xi = x + (((long long)i * 100 + d) * 130 + h) * 64 + w;
#pragma unroll
    for (int kh = 0; kh < 3; ++kh)
      acc = fmaf(cw[(o * 4 + i) * 3 + kh], xi[kh * 64], acc);
  }
  t[idx] = fmaxf(acc, 0.f);
}

// ---------------- big gram (init HOSVD): G = X X^T over fibers ----------------
template<int D, bool TRANS>
__global__ void kgram_big(const float* __restrict__ T, float* __restrict__ part,
                          int P, long long Q) {
  constexpr int C = 64;
  constexpr int SUB = (D + 63) / 64;
  constexpr int DP = SUB * 64;
  __shared__ float tile[DP * (C + 1)];
  const int tid = threadIdx.x;                 // 256
  const int ta = tid >> 4, tb = tid & 15;
  float acc[SUB][SUB][4][4];
#pragma unroll
  for (int a = 0; a < SUB; ++a)
#pragma unroll
    for (int b = 0; b < SUB; ++b)
#pragma unroll
      for (int i = 0; i < 4; ++i)
#pragma unroll
        for (int j = 0; j < 4; ++j) acc[a][b][i][j] = 0.f;

  const long long nfib = (long long)P * Q;
  const int nchunk = (int)(nfib / C);
  for (int ch = blockIdx.x; ch < nchunk; ch += gridDim.x) {
    const long long base = (long long)ch * C;
    __syncthreads();
    if (TRANS) {
      for (int e = tid; e < D * C; e += 256) {
        int a = e & 63, cc = e >> 6;
        tile[a * (C + 1) + cc] = T[base * D + e];
      }
    } else {
      for (int e = tid; e < DP * C; e += 256) {
        int a = e / C, cc = e % C;
        float v = 0.f;
        if (a < D) {
          long long f = base + cc;
          long long p = f / Q, q = f - p * Q;
          v = T[(p * D + a) * Q + q];
        }
        tile[a * (C + 1) + cc] = v;
      }
    }
    __syncthreads();
    for (int cc = 0; cc < C; ++cc) {
      float av[SUB][4], bv[SUB][4];
#pragma unroll
      for (int si = 0; si < SUB; ++si)
#pragma unroll
        for (int i = 0; i < 4; ++i) av[si][i] = tile[(si * 64 + ta * 4 + i) * (C + 1) + cc];
#pragma unroll
      for (int sj = 0; sj < SUB; ++sj)
#pragma unroll
        for (int j = 0; j < 4; ++j) bv[sj][j] = tile[(sj * 64 + tb * 4 + j) * (C + 1) + cc];
#pragma unroll
      for (int si = 0; si < SUB; ++si)
#pragma unroll
        for (int sj = 0; sj < SUB; ++sj)
#pragma unroll
          for (int i = 0; i < 4; ++i)
#pragma unroll
            for (int j = 0; j < 4; ++j)
              acc[si][sj][i][j] = fmaf(av[si][i], bv[sj][j], acc[si][sj][i][j]);
    }
  }
  float* pb = part + (long long)blockIdx.x * D * D;
  for (int si = 0; si < SUB; ++si)
    for (int i = 0; i < 4; ++i) {
      int a = si * 64 + ta * 4 + i;
      if (a >= D) continue;
      for (int sj = 0; sj < SUB; ++sj)
        for (int j = 0; j < 4; ++j) {
          int b = sj * 64 + tb * 4 + j;
          if (b >= D) continue;
          pb[a * D + b] = acc[si][sj][i][j];
        }
    }
}

__global__ void kreduce(const float* __restrict__ part, float* __restrict__ G, int DD) {
  int i = blockIdx.x * blockDim.x + threadIdx.x;
  if (i >= DD) return;
  float s = 0.f;
  for (int b = 0; b < 120; ++b) s += part[(long long)b * DD + i];
  G[i] = s;
}

// ---------------- small gram (projected Y) ----------------
__global__ void kgram_small(const float* __restrict__ Y, float* __restrict__ G,
                            int P, int d, int Q) {
  int pair = blockIdx.x * blockDim.x + threadIdx.x;
  if (pair >= d * d) return;
  int a = pair / d, b = pair % d;
  float s = 0.f;
  for (int p = 0; p < P; ++p) {
    const float* ya = Y + ((long long)p * d + a) * Q;
    const float* yb = Y + ((long long)p * d + b) * Q;
    for (int q = 0; q < Q; ++q) s = fmaf(ya[q], yb[q], s);
  }
  G[pair] = s;
}

// ---------------- mode contraction: out[p,j,q] = sum_a F[a,j] in[p,a,q] ----------------
template<int R>
__global__ void kcontract(const float* __restrict__ in, const float* __restrict__ F,
                          float* __restrict__ out, int P, int d, long long Q) {
  long long total = (long long)P * Q;
  long long idx = (long long)blockIdx.x * blockDim.x + threadIdx.x;
  if (idx >= total) return;
  long long p = idx / Q, q = idx - p * Q;
  float acc[R];
#pragma unroll
  for (int j = 0; j < R; ++j) acc[j] = 0.f;
  const float* ip = in + (p * d) * Q + q;
  for (int a = 0; a < d; ++a) {
    float v = ip[(long long)a * Q];
#pragma unroll
    for (int j = 0; j < R; ++j) acc[j] = fmaf(F[a * R + j], v, acc[j]);
  }
  float* op = out + (p * R) * Q + q;
#pragma unroll
  for (int j = 0; j < R; ++j) op[(long long)j * Q] = acc[j];
}

// ---------------- eigh: top-r eigenvectors of symmetric G (n<=128) ----------------
#define EIG_THREADS 512

struct EigJob { const float* G; float* F; float* Vhh; float* tau; int n; int r; };
struct EigJobs4 { EigJob j[4]; };

__device__ __forceinline__ float blkReduceSum(float v, volatile float* red, int tid) {
  __syncthreads();
#pragma unroll
  for (int off = 32; off > 0; off >>= 1) v += __shfl_down(v, off, 64);
  if ((tid & 63) == 0) red[tid >> 6] = v;
  __syncthreads();
  float s = 0.f;
#pragma unroll
  for (int w = 0; w < EIG_THREADS / 64; ++w) s += red[w];
  return s;
}

__global__ __launch_bounds__(EIG_THREADS)
void keighB(EigJobs4 jobs) {
  const EigJob J = jobs.j[blockIdx.x];
  const int n = J.n, r = J.r;
  const float* __restrict__ G = J.G;
  float* __restrict__ F = J.F;
  float* __restrict__ Vhh = J.Vhh;
  float* __restrict__ tauG = J.tau;

  __shared__ float Apk[8256];
  __shared__ float dd[128], ee[128], e2s[128];
  __shared__ float uu[128], ww[128];
  __shared__ float vt[8][129];        // +1 pad: distinct banks across the 8 solver threads
  __shared__ float slv[8][385];       // u0 @0, u1 @128, u2 @256; stride 385 -> bank offset j
  __shared__ float lam[8];
  __shared__ float red[8];
  __shared__ float sca[4];
  const int tid = threadIdx.x;
  const int lane = tid & 63, wv = tid >> 6;

  // load packed upper triangle: pidx(i,j) = i*n - i(i-1)/2 + (j-i), i<=j
  for (int t = tid; t < n * n; t += EIG_THREADS) {
    int i = t / n, j = t % n;
    if (i <= j) Apk[i * n - ((i * (i - 1)) >> 1) + (j - i)] = G[t];
  }
  __syncthreads();

  // ---- Householder tridiagonalization (LAPACK slarfg conventions) ----
  for (int i = 0; i <= n - 3; ++i) {
    const int cb = i * n - ((i * (i - 1)) >> 1);   // pidx(i,i); column i entry k at cb+(k-i)
    float prt = 0.f;
    for (int k = i + 2 + tid; k < n; k += EIG_THREADS) {
      float v = Apk[cb + (k - i)];
      prt += v * v;
    }
    float xnorm2 = blkReduceSum(prt, red, tid);
    float alpha = Apk[cb + 1];
    float beta, tau_i, scl;
    if (xnorm2 == 0.f) { beta = alpha; tau_i = 0.f; scl = 0.f; }
    else {
      float an = sqrtf(alpha * alpha + xnorm2);
      beta = (alpha >= 0.f) ? -an : an;
      tau_i = (beta - alpha) / beta;
      scl = 1.f / (alpha - beta);
    }
    for (int k = tid; k < n; k += EIG_THREADS) {
      float u = 0.f;
      if (k == i + 1) u = 1.f;
      else if (k >= i + 2) u = Apk[cb + (k - i)] * scl;
      uu[k] = u;
    }
    __syncthreads();
    // w = tau * A_trailing * u ; thread handles k = i+1+tid (l ascending, as round 1)
    {
      int k = i + 1 + tid;
      if (k < n) {
        float s = 0.f;
        int idx = cb + (n - i) + (k - i - 1);        // pidx(i+1, k)
        for (int l = i + 1; l < k; ++l) {            // phase 1: l < k (walk column)
          s = fmaf(Apk[idx], uu[l], s);
          idx += n - l - 1;
        }
        int idx2 = k * n - ((k * (k - 1)) >> 1);     // pidx(k,k): contiguous row
        for (int l = k; l < n; ++l) {
          s = fmaf(Apk[idx2], uu[l], s);
          ++idx2;
        }
        ww[k] = tau_i * s;
      }
    }
    float p2 = 0.f;
    { int k = i + 1 + tid; if (k < n) p2 = ww[k] * uu[k]; }
    float pu = blkReduceSum(p2, red, tid);
    float halfc = -0.5f * tau_i * pu;
    { int k = i + 1 + tid; if (k < n) ww[k] += halfc * uu[k]; }
    __syncthreads();
    // A -= u w^T + w u^T over packed upper triangle of trailing block
    const int mm = n - 1 - i;
    const int M = (mm * (mm + 1)) >> 1;
    const float mmf = 2.f * (float)mm + 1.f;
    for (int t2 = tid; t2 < M; t2 += EIG_THREADS) {
      float disc = fmaf(-8.f, (float)t2, mmf * mmf);
      int a = (int)((mmf - sqrtf(disc)) * 0.5f);
      if (a >= mm) a = mm - 1;
      if (a < 0) a = 0;
      while (a > 0 && (a * mm - ((a * (a - 1)) >> 1)) > t2) --a;
      while (((a + 1) * mm - (((a + 1) * a) >> 1)) <= t2) ++a;
      int b = t2 - (a * mm - ((a * (a - 1)) >> 1)) + a;
      int k = i + 1 + a, l = i + 1 + b;
      int id = k * n - ((k * (k - 1)) >> 1) + (l - k);
      Apk[id] -= uu[k] * ww[l] + ww[k] * uu[l];
    }
    if (tid == 0) { ee[i] = beta; tauG[i] = tau_i; }
    for (int k = tid; k < n; k += EIG_THREADS) Vhh[i * n + k] = uu[k];
    __syncthreads();
  }
  for (int k = tid; k < n; k += EIG_THREADS) dd[k] = Apk[k * n - ((k * (k - 1)) >> 1)];
  if (tid == 0) {
    int k = n - 2;
    ee[n - 2] = Apk[k * n - ((k * (k - 1)) >> 1) + 1];
  }
  __syncthreads();
  // hoisted squared off-diagonals (same rounding as inline e*e)
  for (int k = tid; k < n; k += EIG_THREADS) e2s[k] = (k >= 1) ? ee[k - 1] * ee[k - 1] : 0.f;

  // ---- Gershgorin bounds + pivmin ----
  if (tid == 0) {
    float lo = 3.4e38f, hi = -3.4e38f, me2 = 0.f;
    for (int i = 0; i < n; ++i) {
      float rad = 0.f;
      if (i > 0) rad += fabsf(ee[i - 1]);
      if (i < n - 1) { rad += fabsf(ee[i]); me2 = fmaxf(me2, ee[i] * ee[i]); }
      lo = fminf(lo, dd[i] - rad);
      hi = fmaxf(hi, dd[i] + rad);
    }
    float span = hi - lo;
    sca[0] = lo - 0.001f * span - 1e-20f;
    sca[1] = hi + 0.001f * span + 1e-20f;
    sca[2] = 1.1754944e-38f * fmaxf(1.f, me2);
  }
  __syncthreads();
  const float pivmin = sca[2];

  // ---- Sturm bisection for top-r eigenvalues (unchanged: 40 iters) ----
  if (tid < r) {
    int krank = n - 1 - tid;
    float lo = sca[0], hi = sca[1];
    for (int it = 0; it < 40; ++it) {
      float mid = 0.5f * (lo + hi);
      int cnt = 0;
      float q = dd[0] - mid;
      if (q < 0.f) cnt++;
      for (int i = 1; i < n; ++i) {
        if (fabsf(q) < pivmin) q = -pivmin;
        q = dd[i] - mid - e2s[i] / q;
        if (q < 0.f) cnt++;
      }
      if (cnt > krank) hi = mid; else lo = mid;
    }
    lam[tid] = 0.5f * (lo + hi) * (1.f + (float)tid * 3e-7f);
  }
  __syncthreads();

  // ---- inverse iteration, register-carried recurrence (same op order) ----
  if (tid < r) {
    const int j = tid;
    float* u0 = &slv[j][0];
    float* u1 = &slv[j][128];
    float* u2 = &slv[j][256];
    float* vv = &vt[j][0];
    const float lj = lam[j];
    for (int k = 0; k < n; ++k) vv[k] = 1.f;
    for (int itr = 0; itr < 3; ++itr) {
      float d = dd[0] - lj;          // current u0[i]
      float e = ee[0];               // current u1[i]
      float cv = vv[0];              // current v[i]
      for (int i = 0; i < n - 1; ++i) {
        float bi = ee[i];
        float d1 = dd[i + 1] - lj;                       // u0[i+1] (only step i touches it)
        float e1 = (i + 1 < n - 1) ? ee[i + 1] : 0.f;    // u1[i+1]
        float vnext = vv[i + 1];
        float ai = d, ci = e;
        if (fabsf(ai) >= fabsf(bi)) {
          if (fabsf(ai) < pivmin) ai = (ai >= 0.f ? pivmin : -pivmin);
          float m = bi / ai;
          u0[i] = ai; u1[i] = ci; u2[i] = 0.f;
          d = d1 - m * ci;
          e = e1;
          vv[i] = cv;
          cv = vnext - m * cv;
        } else {
          float m = ai / bi;
          u0[i] = bi; u1[i] = d1; u2[i] = e1;
          d = ci - m * d1;
          e = -m * e1;
          vv[i] = vnext;
          cv = cv - m * vnext;
        }
      }
      if (fabsf(d) < pivmin) d = (d >= 0.f ? pivmin : -pivmin);
      float vi2 = cv / d;                                 // v[n-1]
      vv[n - 1] = vi2;
      float vi1 = (vv[n - 2] - u1[n - 2] * vi2) / u0[n - 2];
      vv[n - 2] = vi1;
      for (int i = n - 3; i >= 0; --i) {
        float t = (vv[i] - u1[i] * vi1 - u2[i] * vi2) / u0[i];
        vv[i] = t;
        vi2 = vi1; vi1 = t;
      }
      float mx = 0.f;
      for (int k = 0; k < n; ++k) mx = fmaxf(mx, fabsf(vv[k]));
      float inv = 1.f / fmaxf(mx, 1e-30f);
      for (int k = 0; k < n; ++k) vv[k] *= inv;
    }
  }
  __syncthreads();

  // ---- MGS orthonormalization (block-parallel, unchanged) ----
  for (int j = 0; j < r; ++j) {
    for (int i = 0; i < j; ++i) {
      float p_ = 0.f;
      for (int k = tid; k < n; k += EIG_THREADS) p_ += vt[i][k] * vt[j][k];
      float dp = blkReduceSum(p_, red, tid);
      for (int k = tid; k < n; k += EIG_THREADS) vt[j][k] -= dp * vt[i][k];
    }
    float p_ = 0.f;
    for (int k = tid; k < n; k += EIG_THREADS) p_ += vt[j][k] * vt[j][k];
    float nn = blkReduceSum(p_, red, tid);
    float inv = rsqrtf(fmaxf(nn, 1e-33f));
    for (int k = tid; k < n; k += EIG_THREADS) vt[j][k] *= inv;
    __syncthreads();
  }

  __threadfence_block();   // make Vhh/tau global writes visible before re-read

  // ---- back-transform: v = H_0 ... H_{n-3} v (one wave per vector) ----
  if (wv < r) {
    float* v = &vt[wv][0];
    for (int h = n - 3; h >= 0; --h) {
      float dp = 0.f;
      for (int k = lane; k < n; k += 64) dp += Vhh[h * n + k] * v[k];
#pragma unroll
      for (int off = 32; off > 0; off >>= 1) dp += __shfl_down(dp, off, 64);
      dp = __shfl(dp, 0, 64);
      float c = tauG[h] * dp;
      for (int k = lane; k < n; k += 64) v[k] -= c * Vhh[h * n + k];
    }
  }
  __syncthreads();

  // ---- canonical sign (max-|component| positive) + write F (n x r) ----
  if (wv < r) {
    float* v = &vt[wv][0];
    float ma = -1.f; int mi = 0x7fffffff;
    for (int k = lane; k < n; k += 64) {
      float a = fabsf(v[k]);
      if (a > ma || (a == ma && k < mi)) { ma = a; mi = k; }
    }
#pragma unroll
    for (int off = 32; off > 0; off >>= 1) {
      float oa = __shfl_down(ma, off, 64);
      int oi = __shfl_down(mi, off, 64);
      if (oa > ma || (oa == ma && oi < mi)) { ma = oa; mi = oi; }
    }
    mi = __shfl(mi, 0, 64);
    float sg = (v[mi] < 0.f) ? -1.f : 1.f;
    for (int k = lane; k < n; k += 64) F[k * r + wv] = sg * v[k];
  }
}

// ---------------------------------------------------------------------------
static inline EigJobs4 one_job(const float* G, float* F, float* V, float* ta, int n, int r) {
  EigJobs4 js;
  js.j[0] = EigJob{G, F, V, ta, n, r};
  js.j[1] = js.j[0]; js.j[2] = js.j[0]; js.j[3] = js.j[0];
  return js;
}

extern "C" void kernel_launch(void* const* d_in, const int* in_sizes, int n_in,
                              void* d_out, int out_size, void* d_ws, size_t ws_size,
                              hipStream_t stream) {
  (void)in_sizes; (void)n_in; (void)out_size; (void)ws_size;
  const float* x  = (const float*)d_in[0];
  const float* cw = (const float*)d_in[1];
  const float* cb = (const float*)d_in[2];
  float* out = (float*)d_out;
  float* ws  = (float*)d_ws;

  float* T    = ws + OFF_T;
  float* TC   = ws + OFF_TC;
  float* TB   = ws + OFF_TB;
  float* PART = ws + OFF_PART;
  float* TD0a = ws + OFF_TD0a;
  float* TD0b = ws + OFF_TD0b;
  float* TD   = ws + OFF_TD;
  float* G0   = ws + OFF_G0;
  float* G1   = ws + OFF_G1;
  float* G2   = ws + OFF_G2;
  float* G3   = ws + OFF_G3;
  float* F0   = ws + OFF_F0;
  float* F1   = ws + OFF_F1;
  float* F2   = ws + OFF_F2;
  float* F3   = ws + OFF_F3;
  float* VHS  = ws + OFF_VHS;
  float* TAS  = ws + OFF_TAS;
  float* VH0  = ws + OFF_VH0;
  float* TA0  = ws + OFF_TA0;

  kconv<<<(26214400 + 255) / 256, 256, 0, stream>>>(x, cw, cb, T);

  // ---- HOSVD init: 4 grams, then one batched 4-block eigh ----
  kgram_big<32, false><<<120, 256, 0, stream>>>(T, PART, 1, 819200);
  kreduce<<<4, 256, 0, stream>>>(PART, G0, 1024);
  kgram_big<100, false><<<120, 256, 0, stream>>>(T, PART, 32, 8192);
  kreduce<<<40, 256, 0, stream>>>(PART, G1, 10000);
  kgram_big<128, false><<<120, 256, 0, stream>>>(T, PART, 3200, 64);
  kreduce<<<64, 256, 0, stream>>>(PART, G2, 16384);
  kgram_big<64, true><<<120, 256, 0, stream>>>(T, PART, 409600, 1);
  kreduce<<<16, 256, 0, stream>>>(PART, G3, 4096);

  {
    EigJobs4 js;
    js.j[0] = EigJob{G0, F0, VH0 + 0 * 16384, TA0 + 0 * 128, 32, 8};
    js.j[1] = EigJob{G1, F1, VH0 + 1 * 16384, TA0 + 1 * 128, 100, 6};
    js.j[2] = EigJob{G2, F2, VH0 + 2 * 16384, TA0 + 2 * 128, 128, 6};
    js.j[3] = EigJob{G3, F3, VH0 + 3 * 16384, TA0 + 3 * 128, 64, 6};
    keighB<<<4, EIG_THREADS, 0, stream>>>(js);
  }

  // ---- HOOI sweeps ----
  for (int sweep = 0; sweep < 5; ++sweep) {
    // mode 0: Y = T x1 F1 x2 F2 x3 F3 -> (32,6,6,6)
    kcontract<6><<<1024, 256, 0, stream>>>(T, F1, TB, 32, 100, 8192);
    kcontract<6><<<48, 256, 0, stream>>>(TB, F2, TD0a, 192, 128, 64);
    kcontract<6><<<5, 256, 0, stream>>>(TD0a, F3, TD0b, 1152, 64, 1);
    kgram_small<<<4, 256, 0, stream>>>(TD0b, G0, 1, 32, 216);
    keighB<<<1, EIG_THREADS, 0, stream>>>(one_job(G0, F0, VHS, TAS, 32, 8));
    // TC = T x0 F0 (reused by modes 1,2,3 and the final core)
    kcontract<8><<<3200, 256, 0, stream>>>(T, F0, TC, 1, 32, 819200);
    // mode 1
    kcontract<6><<<200, 256, 0, stream>>>(TC, F2, TB, 800, 128, 64);
    kcontract<6><<<19, 256, 0, stream>>>(TB, F3, TD, 4800, 64, 1);
    kgram_small<<<40, 256, 0, stream>>>(TD, G0, 8, 100, 36);
    keighB<<<1, EIG_THREADS, 0, stream>>>(one_job(G0, F1, VHS, TAS, 100, 6));
    // mode 2 (TB = TC x1 F1 also reused by mode 3)
    kcontract<6><<<256, 256, 0, stream>>>(TC, F1, TB, 8, 100, 8192);
    kcontract<6><<<24, 256, 0, stream>>>(TB, F3, TD, 6144, 64, 1);
    kgram_small<<<64, 256, 0, stream>>>(TD, G0, 48, 128, 6);
    keighB<<<1, EIG_THREADS, 0, stream>>>(one_job(G0, F2, VHS, TAS, 128, 6));
    // mode 3 (reuses TB from mode 2)
    kcontract<6><<<12, 256, 0, stream>>>(TB, F2, TD, 48, 128, 64);
    kgram_small<<<16, 256, 0, stream>>>(TD, G0, 288, 64, 1);
    keighB<<<1, EIG_THREADS, 0, stream>>>(one_job(G0, F3, VHS, TAS, 64, 6));
  }

  // ---- core = (TC) x1 F1 x2 F2 x3 F3 -> (8,6,6,6) ----
  kcontract<6><<<256, 256, 0, stream>>>(TC, F1, TB, 8, 100, 8192);
  kcontract<6><<<12, 256, 0, stream>>>(TB, F2, TD, 48, 128, 64);
  kcontract<6><<<2, 256, 0, stream>>>(TD, F3, out, 288, 64, 1);
}

// Round 3
// 20746.642 us; speedup vs baseline: 1.1472x; 1.0690x over previous
//
#include <hip/hip_runtime.h>
#include <math.h>

// ---------------------------------------------------------------------------
// TensorProcessor: conv3d(1,3,1)+bias+relu -> Tucker-HOOI core (8,6,6,6)
// Round 3: bitwise-identical arithmetic to rounds 1/2 (absmax 12.375).
// Latency attack on keighB: batched (unrolled) LDS symv loads, Householder
// vectors kept in-place in Apk (no global Vhh/tau), 256-thread block.
// ---------------------------------------------------------------------------

// ws layout (float offsets)
constexpr long long OFF_T   = 0LL;                 // 26,214,400
constexpr long long OFF_TC  = 26214400LL;          // 6,553,600
constexpr long long OFF_TB  = 32768000LL;          // 1,572,864
constexpr long long OFF_PART= OFF_TC;              // 120*16384 (init only)
constexpr long long OFF_TD0a= OFF_TC;              // mode0 (32,6,6,64)=73,728
constexpr long long OFF_TD0b= OFF_TC + 131072;     // mode0 (32,6,6,6)=6,912
constexpr long long OFF_TD  = OFF_TB + 1000000LL;  // sweep small tensors <=36,864
constexpr long long OFF_G0  = OFF_TB + 1400000LL;  // 1,024
constexpr long long OFF_G1  = OFF_G0 + 1024;       // 10,000
constexpr long long OFF_G2  = OFF_G1 + 10000;      // 16,384
constexpr long long OFF_G3  = OFF_G2 + 16384;      // 4,096
constexpr long long OFF_F0  = 34340864LL;          // 256
constexpr long long OFF_F1  = OFF_F0 + 256;        // 600
constexpr long long OFF_F2  = OFF_F1 + 600;        // 768
constexpr long long OFF_F3  = OFF_F2 + 768;        // 384

// ---------------- conv + relu ----------------
__global__ void kconv(const float* __restrict__ x, const float* __restrict__ cw,
                      const float* __restrict__ cb, float* __restrict__ t) {
  int idx = blockIdx.x * blockDim.x + threadIdx.x;
  if (idx >= 26214400) return;
  int w  = idx & 63;
  int h  = (idx >> 6) & 127;
  int d  = (idx >> 13) % 100;
  int o  = idx / 819200;
  float acc = cb[o];
#pragma unroll
  for (int i = 0; i < 4; ++i) {
    const float* xi = x + (((long long)i * 100 + d) * 130 + h) * 64 + w;
#pragma unroll
    for (int kh = 0; kh < 3; ++kh)
      acc = fmaf(cw[(o * 4 + i) * 3 + kh], xi[kh * 64], acc);
  }
  t[idx] = fmaxf(acc, 0.f);
}

// ---------------- big gram (init HOSVD): G = X X^T over fibers ----------------
template<int D, bool TRANS>
__global__ void kgram_big(const float* __restrict__ T, float* __restrict__ part,
                          int P, long long Q) {
  constexpr int C = 64;
  constexpr int SUB = (D + 63) / 64;
  constexpr int DP = SUB * 64;
  __shared__ float tile[DP * (C + 1)];
  const int tid = threadIdx.x;                 // 256
  const int ta = tid >> 4, tb = tid & 15;
  float acc[SUB][SUB][4][4];
#pragma unroll
  for (int a = 0; a < SUB; ++a)
#pragma unroll
    for (int b = 0; b < SUB; ++b)
#pragma unroll
      for (int i = 0; i < 4; ++i)
#pragma unroll
        for (int j = 0; j < 4; ++j) acc[a][b][i][j] = 0.f;

  const long long nfib = (long long)P * Q;
  const int nchunk = (int)(nfib / C);
  for (int ch = blockIdx.x; ch < nchunk; ch += gridDim.x) {
    const long long base = (long long)ch * C;
    __syncthreads();
    if (TRANS) {
      for (int e = tid; e < D * C; e += 256) {
        int a = e & 63, cc = e >> 6;
        tile[a * (C + 1) + cc] = T[base * D + e];
      }
    } else {
      for (int e = tid; e < DP * C; e += 256) {
        int a = e / C, cc = e % C;
        float v = 0.f;
        if (a < D) {
          long long f = base + cc;
          long long p = f / Q, q = f - p * Q;
          v = T[(p * D + a) * Q + q];
        }
        tile[a * (C + 1) + cc] = v;
      }
    }
    __syncthreads();
    for (int cc = 0; cc < C; ++cc) {
      float av[SUB][4], bv[SUB][4];
#pragma unroll
      for (int si = 0; si < SUB; ++si)
#pragma unroll
        for (int i = 0; i < 4; ++i) av[si][i] = tile[(si * 64 + ta * 4 + i) * (C + 1) + cc];
#pragma unroll
      for (int sj = 0; sj < SUB; ++sj)
#pragma unroll
        for (int j = 0; j < 4; ++j) bv[sj][j] = tile[(sj * 64 + tb * 4 + j) * (C + 1) + cc];
#pragma unroll
      for (int si = 0; si < SUB; ++si)
#pragma unroll
        for (int sj = 0; sj < SUB; ++sj)
#pragma unroll
          for (int i = 0; i < 4; ++i)
#pragma unroll
            for (int j = 0; j < 4; ++j)
              acc[si][sj][i][j] = fmaf(av[si][i], bv[sj][j], acc[si][sj][i][j]);
    }
  }
  float* pb = part + (long long)blockIdx.x * D * D;
  for (int si = 0; si < SUB; ++si)
    for (int i = 0; i < 4; ++i) {
      int a = si * 64 + ta * 4 + i;
      if (a >= D) continue;
      for (int sj = 0; sj < SUB; ++sj)
        for (int j = 0; j < 4; ++j) {
          int b = sj * 64 + tb * 4 + j;
          if (b >= D) continue;
          pb[a * D + b] = acc[si][sj][i][j];
        }
    }
}

__global__ void kreduce(const float* __restrict__ part, float* __restrict__ G, int DD) {
  int i = blockIdx.x * blockDim.x + threadIdx.x;
  if (i >= DD) return;
  float s = 0.f;
  for (int b = 0; b < 120; ++b) s += part[(long long)b * DD + i];
  G[i] = s;
}

// ---------------- small gram (projected Y) ----------------
__global__ void kgram_small(const float* __restrict__ Y, float* __restrict__ G,
                            int P, int d, int Q) {
  int pair = blockIdx.x * blockDim.x + threadIdx.x;
  if (pair >= d * d) return;
  int a = pair / d, b = pair % d;
  float s = 0.f;
  for (int p = 0; p < P; ++p) {
    const float* ya = Y + ((long long)p * d + a) * Q;
    const float* yb = Y + ((long long)p * d + b) * Q;
    for (int q = 0; q < Q; ++q) s = fmaf(ya[q], yb[q], s);
  }
  G[pair] = s;
}

// ---------------- mode contraction: out[p,j,q] = sum_a F[a,j] in[p,a,q] ----------------
template<int R>
__global__ void kcontract(const float* __restrict__ in, const float* __restrict__ F,
                          float* __restrict__ out, int P, int d, long long Q) {
  long long total = (long long)P * Q;
  long long idx = (long long)blockIdx.x * blockDim.x + threadIdx.x;
  if (idx >= total) return;
  long long p = idx / Q, q = idx - p * Q;
  float acc[R];
#pragma unroll
  for (int j = 0; j < R; ++j) acc[j] = 0.f;
  const float* ip = in + (p * d) * Q + q;
  for (int a = 0; a < d; ++a) {
    float v = ip[(long long)a * Q];
#pragma unroll
    for (int j = 0; j < R; ++j) acc[j] = fmaf(F[a * R + j], v, acc[j]);
  }
  float* op = out + (p * R) * Q + q;
#pragma unroll
  for (int j = 0; j < R; ++j) op[(long long)j * Q] = acc[j];
}

// ---------------- eigh: top-r eigenvectors of symmetric G (n<=128) ----------------
#define EIG_THREADS 256
#define EIG_WAVES (EIG_THREADS / 64)

struct EigJob { const float* G; float* F; int n; int r; };
struct EigJobs4 { EigJob j[4]; };

__device__ __forceinline__ float blkReduceSum(float v, volatile float* red, int tid) {
  __syncthreads();
#pragma unroll
  for (int off = 32; off > 0; off >>= 1) v += __shfl_down(v, off, 64);
  if ((tid & 63) == 0) red[tid >> 6] = v;
  __syncthreads();
  float s = 0.f;
#pragma unroll
  for (int w = 0; w < EIG_WAVES; ++w) s += red[w];
  return s;
}

__global__ __launch_bounds__(EIG_THREADS)
void keighB(EigJobs4 jobs) {
  const EigJob J = jobs.j[blockIdx.x];
  const int n = J.n, r = J.r;
  const float* __restrict__ G = J.G;
  float* __restrict__ F = J.F;

  __shared__ float Apk[8256];
  __shared__ float dd[128], ee[128], e2s[128];
  __shared__ float uu[128], ww[128];
  __shared__ float scl[128], taus[128];
  __shared__ float vt[8][129];
  __shared__ float slv[8][385];       // u0 @0, u1 @128, u2 @256
  __shared__ float lam[8];
  __shared__ float red[EIG_WAVES];
  __shared__ float sca[4];
  const int tid = threadIdx.x;
  const int lane = tid & 63, wv = tid >> 6;

  // load packed upper triangle: pidx(i,j) = i*n - i(i-1)/2 + (j-i), i<=j
  for (int t = tid; t < n * n; t += EIG_THREADS) {
    int i = t / n, j = t % n;
    if (i <= j) Apk[i * n - ((i * (i - 1)) >> 1) + (j - i)] = G[t];
  }
  __syncthreads();

  // ---- Householder tridiagonalization (LAPACK slarfg conventions) ----
  // Column i of the original matrix (entries pidx(i,k), k>=i+2) is never
  // touched by the trailing update -> Householder vectors stay in-place.
  for (int i = 0; i <= n - 3; ++i) {
    const int cb = i * n - ((i * (i - 1)) >> 1);
    float prt = 0.f;
    { int k = i + 2 + tid; if (k < n) { float v = Apk[cb + (k - i)]; prt = v * v; } }
    float xnorm2 = blkReduceSum(prt, red, tid);
    float alpha = Apk[cb + 1];
    float beta, tau_i, scl_i;
    if (xnorm2 == 0.f) { beta = alpha; tau_i = 0.f; scl_i = 0.f; }
    else {
      float an = sqrtf(alpha * alpha + xnorm2);
      beta = (alpha >= 0.f) ? -an : an;
      tau_i = (beta - alpha) / beta;
      scl_i = 1.f / (alpha - beta);
    }
    { int k = tid;
      if (k < n) {
        float u = 0.f;
        if (k == i + 1) u = 1.f;
        else if (k >= i + 2) u = Apk[cb + (k - i)] * scl_i;
        uu[k] = u;
      } }
    __syncthreads();
    // w = tau * A_trailing * u ; batched loads, fma order = l ascending
    {
      int k = i + 1 + tid;
      if (k < n) {
        float s = 0.f;
        // phase 1: l in [i+1, k): walk column k (stride n-l-1)
        int l = i + 1;
        int idx = cb + (n - i) + (k - i - 1);        // pidx(i+1, k)
        for (; l + 4 <= k; l += 4) {
          int j0 = idx;
          int j1 = j0 + (n - l - 1);
          int j2 = j1 + (n - l - 2);
          int j3 = j2 + (n - l - 3);
          idx = j3 + (n - l - 4);
          float A0 = Apk[j0], A1 = Apk[j1], A2 = Apk[j2], A3 = Apk[j3];
          float U0 = uu[l], U1 = uu[l + 1], U2 = uu[l + 2], U3 = uu[l + 3];
          s = fmaf(A0, U0, s); s = fmaf(A1, U1, s);
          s = fmaf(A2, U2, s); s = fmaf(A3, U3, s);
        }
        for (; l < k; ++l) { s = fmaf(Apk[idx], uu[l], s); idx += n - l - 1; }
        // phase 2: l in [k, n): contiguous row from pidx(k,k)
        int idx2 = k * n - ((k * (k - 1)) >> 1);
        int l2 = k;
        for (; l2 + 8 <= n; l2 += 8) {
          float A0 = Apk[idx2],     A1 = Apk[idx2 + 1], A2 = Apk[idx2 + 2], A3 = Apk[idx2 + 3];
          float A4 = Apk[idx2 + 4], A5 = Apk[idx2 + 5], A6 = Apk[idx2 + 6], A7 = Apk[idx2 + 7];
          float U0 = uu[l2],     U1 = uu[l2 + 1], U2 = uu[l2 + 2], U3 = uu[l2 + 3];
          float U4 = uu[l2 + 4], U5 = uu[l2 + 5], U6 = uu[l2 + 6], U7 = uu[l2 + 7];
          s = fmaf(A0, U0, s); s = fmaf(A1, U1, s); s = fmaf(A2, U2, s); s = fmaf(A3, U3, s);
          s = fmaf(A4, U4, s); s = fmaf(A5, U5, s); s = fmaf(A6, U6, s); s = fmaf(A7, U7, s);
          idx2 += 8;
        }
        for (; l2 < n; ++l2) { s = fmaf(Apk[idx2], uu[l2], s); ++idx2; }
        ww[k] = tau_i * s;
      }
    }
    float p2 = 0.f;
    { int k = i + 1 + tid; if (k < n) p2 = ww[k] * uu[k]; }
    float pu = blkReduceSum(p2, red, tid);
    float halfc = -0.5f * tau_i * pu;
    { int k = i + 1 + tid; if (k < n) ww[k] += halfc * uu[k]; }
    __syncthreads();
    // A -= u w^T + w u^T over packed upper triangle of trailing block
    const int mm = n - 1 - i;
    const int M = (mm * (mm + 1)) >> 1;
    const float mmf = 2.f * (float)mm + 1.f;
    for (int t2 = tid; t2 < M; t2 += EIG_THREADS) {
      float disc = fmaf(-8.f, (float)t2, mmf * mmf);
      int a = (int)((mmf - sqrtf(disc)) * 0.5f);
      if (a >= mm) a = mm - 1;
      if (a < 0) a = 0;
      while (a > 0 && (a * mm - ((a * (a - 1)) >> 1)) > t2) --a;
      while (((a + 1) * mm - (((a + 1) * a) >> 1)) <= t2) ++a;
      int b = t2 - (a * mm - ((a * (a - 1)) >> 1)) + a;
      int k = i + 1 + a, l = i + 1 + b;
      int id = k * n - ((k * (k - 1)) >> 1) + (l - k);
      Apk[id] -= uu[k] * ww[l] + ww[k] * uu[l];
    }
    if (tid == 0) { ee[i] = beta; taus[i] = tau_i; scl[i] = scl_i; }
    __syncthreads();
  }
  { int k = tid; if (k < n) dd[k] = Apk[k * n - ((k * (k - 1)) >> 1)]; }
  if (tid == 0) {
    int k = n - 2;
    ee[n - 2] = Apk[k * n - ((k * (k - 1)) >> 1) + 1];
  }
  __syncthreads();
  { int k = tid; if (k < n) e2s[k] = (k >= 1) ? ee[k - 1] * ee[k - 1] : 0.f; }

  // ---- Gershgorin bounds + pivmin ----
  if (tid == 0) {
    float lo = 3.4e38f, hi = -3.4e38f, me2 = 0.f;
    for (int i = 0; i < n; ++i) {
      float rad = 0.f;
      if (i > 0) rad += fabsf(ee[i - 1]);
      if (i < n - 1) { rad += fabsf(ee[i]); me2 = fmaxf(me2, ee[i] * ee[i]); }
      lo = fminf(lo, dd[i] - rad);
      hi = fmaxf(hi, dd[i] + rad);
    }
    float span = hi - lo;
    sca[0] = lo - 0.001f * span - 1e-20f;
    sca[1] = hi + 0.001f * span + 1e-20f;
    sca[2] = 1.1754944e-38f * fmaxf(1.f, me2);
  }
  __syncthreads();
  const float pivmin = sca[2];

  // ---- Sturm bisection for top-r eigenvalues ----
  if (tid < r) {
    int krank = n - 1 - tid;
    float lo = sca[0], hi = sca[1];
    for (int it = 0; it < 40; ++it) {
      float mid = 0.5f * (lo + hi);
      int cnt = 0;
      float q = dd[0] - mid;
      if (q < 0.f) cnt++;
      for (int i = 1; i < n; ++i) {
        if (fabsf(q) < pivmin) q = -pivmin;
        q = dd[i] - mid - e2s[i] / q;
        if (q < 0.f) cnt++;
      }
      if (cnt > krank) hi = mid; else lo = mid;
    }
    lam[tid] = 0.5f * (lo + hi) * (1.f + (float)tid * 3e-7f);
  }
  __syncthreads();

  // ---- inverse iteration, register-carried recurrence ----
  if (tid < r) {
    const int j = tid;
    float* u0 = &slv[j][0];
    float* u1 = &slv[j][128];
    float* u2 = &slv[j][256];
    float* vv = &vt[j][0];
    const float lj = lam[j];
    for (int k = 0; k < n; ++k) vv[k] = 1.f;
    for (int itr = 0; itr < 3; ++itr) {
      float d = dd[0] - lj;
      float e = ee[0];
      float cv = vv[0];
      for (int i = 0; i < n - 1; ++i) {
        float bi = ee[i];
        float d1 = dd[i + 1] - lj;
        float e1 = (i + 1 < n - 1) ? ee[i + 1] : 0.f;
        float vnext = vv[i + 1];
        float ai = d, ci = e;
        if (fabsf(ai) >= fabsf(bi)) {
          if (fabsf(ai) < pivmin) ai = (ai >= 0.f ? pivmin : -pivmin);
          float m = bi / ai;
          u0[i] = ai; u1[i] = ci; u2[i] = 0.f;
          d = d1 - m * ci;
          e = e1;
          vv[i] = cv;
          cv = vnext - m * cv;
        } else {
          float m = ai / bi;
          u0[i] = bi; u1[i] = d1; u2[i] = e1;
          d = ci - m * d1;
          e = -m * e1;
          vv[i] = vnext;
          cv = cv - m * vnext;
        }
      }
      if (fabsf(d) < pivmin) d = (d >= 0.f ? pivmin : -pivmin);
      float vi2 = cv / d;
      vv[n - 1] = vi2;
      float vi1 = (vv[n - 2] - u1[n - 2] * vi2) / u0[n - 2];
      vv[n - 2] = vi1;
      for (int i = n - 3; i >= 0; --i) {
        float t = (vv[i] - u1[i] * vi1 - u2[i] * vi2) / u0[i];
        vv[i] = t;
        vi2 = vi1; vi1 = t;
      }
      float mx = 0.f;
      for (int k = 0; k < n; ++k) mx = fmaxf(mx, fabsf(vv[k]));
      float inv = 1.f / fmaxf(mx, 1e-30f);
      for (int k = 0; k < n; ++k) vv[k] *= inv;
    }
  }
  __syncthreads();

  // ---- MGS orthonormalization (block-parallel) ----
  for (int j = 0; j < r; ++j) {
    for (int i = 0; i < j; ++i) {
      float p_ = 0.f;
      { int k = tid; if (k < n) p_ = vt[i][k] * vt[j][k]; }
      float dp = blkReduceSum(p_, red, tid);
      { int k = tid; if (k < n) vt[j][k] -= dp * vt[i][k]; }
    }
    float p_ = 0.f;
    { int k = tid; if (k < n) p_ = vt[j][k] * vt[j][k]; }
    float nn = blkReduceSum(p_, red, tid);
    float inv = rsqrtf(fmaxf(nn, 1e-33f));
    { int k = tid; if (k < n) vt[j][k] *= inv; }
    __syncthreads();
  }

  // ---- back-transform: v = H_0 ... H_{n-3} v; u recomputed from Apk rows ----
  for (int vec = wv; vec < r; vec += EIG_WAVES) {
    float* v = &vt[vec][0];
    for (int h = n - 3; h >= 0; --h) {
      const int cbh = h * n - ((h * (h - 1)) >> 1);
      const float sh = scl[h];
      float dp = 0.f;
      for (int k = lane; k < n; k += 64) {
        float uk = (k <= h) ? 0.f : ((k == h + 1) ? 1.f : Apk[cbh + (k - h)] * sh);
        dp += uk * v[k];
      }
#pragma unroll
      for (int off = 32; off > 0; off >>= 1) dp += __shfl_down(dp, off, 64);
      dp = __shfl(dp, 0, 64);
      float c = taus[h] * dp;
      for (int k = lane; k < n; k += 64) {
        float uk = (k <= h) ? 0.f : ((k == h + 1) ? 1.f : Apk[cbh + (k - h)] * sh);
        v[k] -= c * uk;
      }
    }
  }
  __syncthreads();

  // ---- canonical sign (max-|component| positive) + write F (n x r) ----
  for (int vec = wv; vec < r; vec += EIG_WAVES) {
    float* v = &vt[vec][0];
    float ma = -1.f; int mi = 0x7fffffff;
    for (int k = lane; k < n; k += 64) {
      float a = fabsf(v[k]);
      if (a > ma || (a == ma && k < mi)) { ma = a; mi = k; }
    }
#pragma unroll
    for (int off = 32; off > 0; off >>= 1) {
      float oa = __shfl_down(ma, off, 64);
      int oi = __shfl_down(mi, off, 64);
      if (oa > ma || (oa == ma && oi < mi)) { ma = oa; mi = oi; }
    }
    mi = __shfl(mi, 0, 64);
    float sg = (v[mi] < 0.f) ? -1.f : 1.f;
    for (int k = lane; k < n; k += 64) F[k * r + vec] = sg * v[k];
  }
}

// ---------------------------------------------------------------------------
static inline EigJobs4 one_job(const float* G, float* F, int n, int r) {
  EigJobs4 js;
  js.j[0] = EigJob{G, F, n, r};
  js.j[1] = js.j[0]; js.j[2] = js.j[0]; js.j[3] = js.j[0];
  return js;
}

extern "C" void kernel_launch(void* const* d_in, const int* in_sizes, int n_in,
                              void* d_out, int out_size, void* d_ws, size_t ws_size,
                              hipStream_t stream) {
  (void)in_sizes; (void)n_in; (void)out_size; (void)ws_size;
  const float* x  = (const float*)d_in[0];
  const float* cw = (const float*)d_in[1];
  const float* cb = (const float*)d_in[2];
  float* out = (float*)d_out;
  float* ws  = (float*)d_ws;

  float* T    = ws + OFF_T;
  float* TC   = ws + OFF_TC;
  float* TB   = ws + OFF_TB;
  float* PART = ws + OFF_PART;
  float* TD0a = ws + OFF_TD0a;
  float* TD0b = ws + OFF_TD0b;
  float* TD   = ws + OFF_TD;
  float* G0   = ws + OFF_G0;
  float* G1   = ws + OFF_G1;
  float* G2   = ws + OFF_G2;
  float* G3   = ws + OFF_G3;
  float* F0   = ws + OFF_F0;
  float* F1   = ws + OFF_F1;
  float* F2   = ws + OFF_F2;
  float* F3   = ws + OFF_F3;

  kconv<<<(26214400 + 255) / 256, 256, 0, stream>>>(x, cw, cb, T);

  // ---- HOSVD init: 4 grams, then one batched 4-block eigh ----
  kgram_big<32, false><<<120, 256, 0, stream>>>(T, PART, 1, 819200);
  kreduce<<<4, 256, 0, stream>>>(PART, G0, 1024);
  kgram_big<100, false><<<120, 256, 0, stream>>>(T, PART, 32, 8192);
  kreduce<<<40, 256, 0, stream>>>(PART, G1, 10000);
  kgram_big<128, false><<<120, 256, 0, stream>>>(T, PART, 3200, 64);
  kreduce<<<64, 256, 0, stream>>>(PART, G2, 16384);
  kgram_big<64, true><<<120, 256, 0, stream>>>(T, PART, 409600, 1);
  kreduce<<<16, 256, 0, stream>>>(PART, G3, 4096);

  {
    EigJobs4 js;
    js.j[0] = EigJob{G0, F0, 32, 8};
    js.j[1] = EigJob{G1, F1, 100, 6};
    js.j[2] = EigJob{G2, F2, 128, 6};
    js.j[3] = EigJob{G3, F3, 64, 6};
    keighB<<<4, EIG_THREADS, 0, stream>>>(js);
  }

  // ---- HOOI sweeps ----
  for (int sweep = 0; sweep < 5; ++sweep) {
    // mode 0: Y = T x1 F1 x2 F2 x3 F3 -> (32,6,6,6)
    kcontract<6><<<1024, 256, 0, stream>>>(T, F1, TB, 32, 100, 8192);
    kcontract<6><<<48, 256, 0, stream>>>(TB, F2, TD0a, 192, 128, 64);
    kcontract<6><<<5, 256, 0, stream>>>(TD0a, F3, TD0b, 1152, 64, 1);
    kgram_small<<<4, 256, 0, stream>>>(TD0b, G0, 1, 32, 216);
    keighB<<<1, EIG_THREADS, 0, stream>>>(one_job(G0, F0, 32, 8));
    // TC = T x0 F0 (reused by modes 1,2,3 and the final core)
    kcontract<8><<<3200, 256, 0, stream>>>(T, F0, TC, 1, 32, 819200);
    // mode 1
    kcontract<6><<<200, 256, 0, stream>>>(TC, F2, TB, 800, 128, 64);
    kcontract<6><<<19, 256, 0, stream>>>(TB, F3, TD, 4800, 64, 1);
    kgram_small<<<40, 256, 0, stream>>>(TD, G0, 8, 100, 36);
    keighB<<<1, EIG_THREADS, 0, stream>>>(one_job(G0, F1, 100, 6));
    // mode 2 (TB = TC x1 F1 also reused by mode 3)
    kcontract<6><<<256, 256, 0, stream>>>(TC, F1, TB, 8, 100, 8192);
    kcontract<6><<<24, 256, 0, stream>>>(TB, F3, TD, 6144, 64, 1);
    kgram_small<<<64, 256, 0, stream>>>(TD, G0, 48, 128, 6);
    keighB<<<1, EIG_THREADS, 0, stream>>>(one_job(G0, F2, 128, 6));
    // mode 3 (reuses TB from mode 2)
    kcontract<6><<<12, 256, 0, stream>>>(TB, F2, TD, 48, 128, 64);
    kgram_small<<<16, 256, 0, stream>>>(TD, G0, 288, 64, 1);
    keighB<<<1, EIG_THREADS, 0, stream>>>(one_job(G0, F3, 64, 6));
  }

  // ---- core = (TC) x1 F1 x2 F2 x3 F3 -> (8,6,6,6) ----
  kcontract<6><<<256, 256, 0, stream>>>(TC, F1, TB, 8, 100, 8192);
  kcontract<6><<<12, 256, 0, stream>>>(TB, F2, TD, 48, 128, 64);
  kcontract<6><<<2, 256, 0, stream>>>(TD, F3, out, 288, 64, 1);
}

// Round 4
// 18712.451 us; speedup vs baseline: 1.2719x; 1.1087x over previous
//
#include <hip/hip_runtime.h>
#include <math.h>

// ---------------------------------------------------------------------------
// TensorProcessor: conv3d(1,3,1)+bias+relu -> Tucker-HOOI core (8,6,6,6)
// Round 4: register-resident Householder tridiagonalization (row k of the
// full symmetric matrix lives in thread k's VGPRs; templated N for full
// unroll), symmetric-exact updates, 33-way multisection eigenvalues.
// Tail phases (invit/MGS/back-transform/canonical sign) unchanged from R3.
// ---------------------------------------------------------------------------

// ws layout (float offsets)
constexpr long long OFF_T   = 0LL;                 // 26,214,400
constexpr long long OFF_TC  = 26214400LL;          // 6,553,600
constexpr long long OFF_TB  = 32768000LL;          // 1,572,864
constexpr long long OFF_PART= OFF_TC;              // 120*16384 (init only)
constexpr long long OFF_TD0a= OFF_TC;              // mode0 (32,6,6,64)=73,728
constexpr long long OFF_TD0b= OFF_TC + 131072;     // mode0 (32,6,6,6)=6,912
constexpr long long OFF_TD  = OFF_TB + 1000000LL;  // sweep small tensors
constexpr long long OFF_G0  = OFF_TB + 1400000LL;  // 1,024
constexpr long long OFF_G1  = OFF_G0 + 1024;       // 10,000
constexpr long long OFF_G2  = OFF_G1 + 10000;      // 16,384
constexpr long long OFF_G3  = OFF_G2 + 16384;      // 4,096
constexpr long long OFF_F0  = 34340864LL;          // 256
constexpr long long OFF_F1  = OFF_F0 + 256;        // 600
constexpr long long OFF_F2  = OFF_F1 + 600;        // 768
constexpr long long OFF_F3  = OFF_F2 + 768;        // 384

// ---------------- conv + relu ----------------
__global__ void kconv(const float* __restrict__ x, const float* __restrict__ cw,
                      const float* __restrict__ cb, float* __restrict__ t) {
  int idx = blockIdx.x * blockDim.x + threadIdx.x;
  if (idx >= 26214400) return;
  int w  = idx & 63;
  int h  = (idx >> 6) & 127;
  int d  = (idx >> 13) % 100;
  int o  = idx / 819200;
  float acc = cb[o];
#pragma unroll
  for (int i = 0; i < 4; ++i) {
    const float* xi = x + (((long long)i * 100 + d) * 130 + h) * 64 + w;
#pragma unroll
    for (int kh = 0; kh < 3; ++kh)
      acc = fmaf(cw[(o * 4 + i) * 3 + kh], xi[kh * 64], acc);
  }
  t[idx] = fmaxf(acc, 0.f);
}

// ---------------- big gram (init HOSVD): G = X X^T over fibers ----------------
template<int D, bool TRANS>
__global__ void kgram_big(const float* __restrict__ T, float* __restrict__ part,
                          int P, long long Q) {
  constexpr int C = 64;
  constexpr int SUB = (D + 63) / 64;
  constexpr int DP = SUB * 64;
  __shared__ float tile[DP * (C + 1)];
  const int tid = threadIdx.x;                 // 256
  const int ta = tid >> 4, tb = tid & 15;
  float acc[SUB][SUB][4][4];
#pragma unroll
  for (int a = 0; a < SUB; ++a)
#pragma unroll
    for (int b = 0; b < SUB; ++b)
#pragma unroll
      for (int i = 0; i < 4; ++i)
#pragma unroll
        for (int j = 0; j < 4; ++j) acc[a][b][i][j] = 0.f;

  const long long nfib = (long long)P * Q;
  const int nchunk = (int)(nfib / C);
  for (int ch = blockIdx.x; ch < nchunk; ch += gridDim.x) {
    const long long base = (long long)ch * C;
    __syncthreads();
    if (TRANS) {
      for (int e = tid; e < D * C; e += 256) {
        int a = e & 63, cc = e >> 6;
        tile[a * (C + 1) + cc] = T[base * D + e];
      }
    } else {
      for (int e = tid; e < DP * C; e += 256) {
        int a = e / C, cc = e % C;
        float v = 0.f;
        if (a < D) {
          long long f = base + cc;
          long long p = f / Q, q = f - p * Q;
          v = T[(p * D + a) * Q + q];
        }
        tile[a * (C + 1) + cc] = v;
      }
    }
    __syncthreads();
    for (int cc = 0; cc < C; ++cc) {
      float av[SUB][4], bv[SUB][4];
#pragma unroll
      for (int si = 0; si < SUB; ++si)
#pragma unroll
        for (int i = 0; i < 4; ++i) av[si][i] = tile[(si * 64 + ta * 4 + i) * (C + 1) + cc];
#pragma unroll
      for (int sj = 0; sj < SUB; ++sj)
#pragma unroll
        for (int j = 0; j < 4; ++j) bv[sj][j] = tile[(sj * 64 + tb * 4 + j) * (C + 1) + cc];
#pragma unroll
      for (int si = 0; si < SUB; ++si)
#pragma unroll
        for (int sj = 0; sj < SUB; ++sj)
#pragma unroll
          for (int i = 0; i < 4; ++i)
#pragma unroll
            for (int j = 0; j < 4; ++j)
              acc[si][sj][i][j] = fmaf(av[si][i], bv[sj][j], acc[si][sj][i][j]);
    }
  }
  float* pb = part + (long long)blockIdx.x * D * D;
  for (int si = 0; si < SUB; ++si)
    for (int i = 0; i < 4; ++i) {
      int a = si * 64 + ta * 4 + i;
      if (a >= D) continue;
      for (int sj = 0; sj < SUB; ++sj)
        for (int j = 0; j < 4; ++j) {
          int b = sj * 64 + tb * 4 + j;
          if (b >= D) continue;
          pb[a * D + b] = acc[si][sj][i][j];
        }
    }
}

__global__ void kreduce(const float* __restrict__ part, float* __restrict__ G, int DD) {
  int i = blockIdx.x * blockDim.x + threadIdx.x;
  if (i >= DD) return;
  float s = 0.f;
  for (int b = 0; b < 120; ++b) s += part[(long long)b * DD + i];
  G[i] = s;
}

// ---------------- small gram (projected Y) ----------------
__global__ void kgram_small(const float* __restrict__ Y, float* __restrict__ G,
                            int P, int d, int Q) {
  int pair = blockIdx.x * blockDim.x + threadIdx.x;
  if (pair >= d * d) return;
  int a = pair / d, b = pair % d;
  float s = 0.f;
  for (int p = 0; p < P; ++p) {
    const float* ya = Y + ((long long)p * d + a) * Q;
    const float* yb = Y + ((long long)p * d + b) * Q;
    for (int q = 0; q < Q; ++q) s = fmaf(ya[q], yb[q], s);
  }
  G[pair] = s;
}

// ---------------- mode contraction: out[p,j,q] = sum_a F[a,j] in[p,a,q] ----------------
template<int R>
__global__ void kcontract(const float* __restrict__ in, const float* __restrict__ F,
                          float* __restrict__ out, int P, int d, long long Q) {
  long long total = (long long)P * Q;
  long long idx = (long long)blockIdx.x * blockDim.x + threadIdx.x;
  if (idx >= total) return;
  long long p = idx / Q, q = idx - p * Q;
  float acc[R];
#pragma unroll
  for (int j = 0; j < R; ++j) acc[j] = 0.f;
  const float* ip = in + (p * d) * Q + q;
  for (int a = 0; a < d; ++a) {
    float v = ip[(long long)a * Q];
#pragma unroll
    for (int j = 0; j < R; ++j) acc[j] = fmaf(F[a * R + j], v, acc[j]);
  }
  float* op = out + (p * R) * Q + q;
#pragma unroll
  for (int j = 0; j < R; ++j) op[(long long)j * Q] = acc[j];
}

// ---------------- eigh: top-r eigenvectors of symmetric G (n<=128) ----------------
#define EIG_THREADS 256
#define EIG_WAVES 4

struct ESm {
  float ApkL[8256];              // packed-lower Householder columns (export)
  float dd[128], ee[128], e2s[128];
  float colbuf[128];             // current pivot column (= dumped row)
  float uu[128];
  float2 uw[128];
  float taus[128], scls[128];
  float vt[8][129];
  float slv[8][385];
  float lam[8];
  float red[EIG_WAVES];
  float sca[4];
};

// reduce WITHOUT entry barrier (caller guarantees arg-LDS already synced)
__device__ __forceinline__ float blkReduceSumNB(float v, volatile float* red, int tid) {
#pragma unroll
  for (int off = 32; off > 0; off >>= 1) v += __shfl_down(v, off, 64);
  if ((tid & 63) == 0) red[tid >> 6] = v;
  __syncthreads();
  float s = 0.f;
#pragma unroll
  for (int w = 0; w < EIG_WAVES; ++w) s += red[w];
  return s;
}

__device__ __forceinline__ float blkReduceSum(float v, volatile float* red, int tid) {
  __syncthreads();
  return blkReduceSumNB(v, red, tid);
}

template<int N, int RR>
__device__ void eig_body(ESm& S, const float* __restrict__ G, float* __restrict__ F) {
  const int tid = threadIdx.x;
  const int lane = tid & 63, wv = tid >> 6;

  // ---- load: thread k owns row k of the full symmetric matrix in VGPRs ----
  float Ar[N];
  if (tid < N) {
#pragma unroll
    for (int l = 0; l < N; ++l) Ar[l] = G[tid * N + l];
  } else {
#pragma unroll
    for (int l = 0; l < N; ++l) Ar[l] = 0.f;
  }
  if (tid == 0) {
#pragma unroll
    for (int l = 0; l < N; ++l) S.colbuf[l] = Ar[l];   // column 0 = row 0
  }

  // ---- Householder tridiagonalization (LAPACK slarfg conventions) ----
  for (int i = 0; i <= N - 3; ++i) {
    __syncthreads();                                   // colbuf / prev-step visible
    float prt = 0.f;
    { int k2 = i + 2 + tid; if (k2 < N) { float v = S.colbuf[k2]; prt = v * v; } }
    float xnorm2 = blkReduceSumNB(prt, S.red, tid);
    float alpha = S.colbuf[i + 1];
    float beta, tau_i, scl_i;
    if (xnorm2 == 0.f) { beta = alpha; tau_i = 0.f; scl_i = 0.f; }
    else {
      float an = sqrtf(alpha * alpha + xnorm2);
      beta = (alpha >= 0.f) ? -an : an;
      tau_i = (beta - alpha) / beta;
      scl_i = 1.f / (alpha - beta);
    }
    float u_loc = 0.f;
    if (tid == i + 1) u_loc = 1.f;
    else if (tid >= i + 2 && tid < N) u_loc = S.colbuf[tid] * scl_i;
    if (tid < 128) S.uu[tid] = u_loc;
    __syncthreads();
    // symv from registers: zero-extended to l=0..N-1 (uu[l]=0 for l<=i: exact no-op)
    float s = 0.f;
    if (tid < N) {
#pragma unroll
      for (int l = 0; l < N; ++l) s = fmaf(Ar[l], S.uu[l], s);
    }
    float w_pre = (tid >= i + 1 && tid < N) ? tau_i * s : 0.f;
    if (tid < 128) S.uw[tid] = make_float2(u_loc, w_pre);
    __syncthreads();
    float p2 = 0.f;
    { int kk = i + 1 + tid; if (kk < N) { float2 t = S.uw[kk]; p2 = t.y * t.x; } }
    float pu = blkReduceSumNB(p2, S.red, tid);
    float halfc = -0.5f * tau_i * pu;
    float w_fin = w_pre + halfc * u_loc;
    if (tid < 128) S.uw[tid].y = w_fin;
    __syncthreads();
    // trailing update, register-resident, symmetric-exact expression
    if (tid < N) {
#pragma unroll
      for (int l = 0; l < N; ++l) {
        float2 p = S.uw[l];
        Ar[l] -= __fadd_rn(__fmul_rn(u_loc, p.y), __fmul_rn(w_fin, p.x));
      }
      if (tid == i + 1) {                     // next step's pivot column = my row
#pragma unroll
        for (int l = 0; l < N; ++l) S.colbuf[l] = Ar[l];
      }
    }
    if (tid == 0) { S.ee[i] = beta; S.taus[i] = tau_i; S.scls[i] = scl_i; }
  }
  __syncthreads();

  // ---- export diag + packed-lower Householder columns to LDS ----
  if (tid < N) {
    float dv = 0.f;
#pragma unroll
    for (int l = 0; l < N; ++l) if (l == tid) dv = Ar[l];
    S.dd[tid] = dv;
    int base = (tid * (tid - 1)) >> 1;
#pragma unroll
    for (int h = 0; h < N; ++h) if (h < tid) S.ApkL[base + h] = Ar[h];
  }
  if (tid == N - 1) S.ee[N - 2] = Ar[N - 2];
  __syncthreads();
  if (tid < N) S.e2s[tid] = (tid >= 1) ? S.ee[tid - 1] * S.ee[tid - 1] : 0.f;

  // ---- Gershgorin bounds + pivmin ----
  if (tid == 0) {
    float lo = 3.4e38f, hi = -3.4e38f, me2 = 0.f;
    for (int ii = 0; ii < N; ++ii) {
      float rad = 0.f;
      if (ii > 0) rad += fabsf(S.ee[ii - 1]);
      if (ii < N - 1) { rad += fabsf(S.ee[ii]); me2 = fmaxf(me2, S.ee[ii] * S.ee[ii]); }
      lo = fminf(lo, S.dd[ii] - rad);
      hi = fmaxf(hi, S.dd[ii] + rad);
    }
    float span = hi - lo;
    S.sca[0] = lo - 0.001f * span - 1e-20f;
    S.sca[1] = hi + 0.001f * span + 1e-20f;
    S.sca[2] = 1.1754944e-38f * fmaxf(1.f, me2);
  }
  __syncthreads();
  const float pivmin = S.sca[2];

  // ---- 33-way multisection: 32 threads per eigenvalue, 8 rounds ----
  {
    const int grp = tid >> 5, gt = tid & 31;
    if (grp < RR) {
      const int krank = N - 1 - grp;
      float lo = S.sca[0], hi = S.sca[1];
      for (int round = 0; round < 8; ++round) {
        float w = (hi - lo) * (1.f / 33.f);
        float sg = fmaf(w, (float)(gt + 1), lo);
        int cnt = 0;
        float q = S.dd[0] - sg;
        if (q < 0.f) cnt++;
        for (int ii = 1; ii < N; ++ii) {
          if (fabsf(q) < pivmin) q = -pivmin;
          q = S.dd[ii] - sg - S.e2s[ii] / q;
          if (q < 0.f) cnt++;
        }
        float nlo = (cnt <= krank) ? sg : lo;
        float nhi = (cnt >  krank) ? sg : hi;
#pragma unroll
        for (int off = 16; off > 0; off >>= 1) {
          nlo = fmaxf(nlo, __shfl_down(nlo, off, 32));
          nhi = fminf(nhi, __shfl_down(nhi, off, 32));
        }
        nlo = __shfl(nlo, 0, 32);
        nhi = __shfl(nhi, 0, 32);
        lo = fminf(nlo, nhi); hi = fmaxf(nlo, nhi);
      }
      if (gt == 0) S.lam[grp] = 0.5f * (lo + hi) * (1.f + (float)grp * 3e-7f);
    }
  }
  __syncthreads();

  // ---- inverse iteration, register-carried recurrence ----
  if (tid < RR) {
    const int j = tid;
    float* u0 = &S.slv[j][0];
    float* u1 = &S.slv[j][128];
    float* u2 = &S.slv[j][256];
    float* vv = &S.vt[j][0];
    const float lj = S.lam[j];
    for (int k = 0; k < N; ++k) vv[k] = 1.f;
    for (int itr = 0; itr < 3; ++itr) {
      float d = S.dd[0] - lj;
      float e = S.ee[0];
      float cv = vv[0];
      for (int i = 0; i < N - 1; ++i) {
        float bi = S.ee[i];
        float d1 = S.dd[i + 1] - lj;
        float e1 = (i + 1 < N - 1) ? S.ee[i + 1] : 0.f;
        float vnext = vv[i + 1];
        float ai = d, ci = e;
        if (fabsf(ai) >= fabsf(bi)) {
          if (fabsf(ai) < pivmin) ai = (ai >= 0.f ? pivmin : -pivmin);
          float m = bi / ai;
          u0[i] = ai; u1[i] = ci; u2[i] = 0.f;
          d = d1 - m * ci;
          e = e1;
          vv[i] = cv;
          cv = vnext - m * cv;
        } else {
          float m = ai / bi;
          u0[i] = bi; u1[i] = d1; u2[i] = e1;
          d = ci - m * d1;
          e = -m * e1;
          vv[i] = vnext;
          cv = cv - m * vnext;
        }
      }
      if (fabsf(d) < pivmin) d = (d >= 0.f ? pivmin : -pivmin);
      float vi2 = cv / d;
      vv[N - 1] = vi2;
      float vi1 = (vv[N - 2] - u1[N - 2] * vi2) / u0[N - 2];
      vv[N - 2] = vi1;
      for (int i = N - 3; i >= 0; --i) {
        float t = (vv[i] - u1[i] * vi1 - u2[i] * vi2) / u0[i];
        vv[i] = t;
        vi2 = vi1; vi1 = t;
      }
      float mx = 0.f;
      for (int k = 0; k < N; ++k) mx = fmaxf(mx, fabsf(vv[k]));
      float inv = 1.f / fmaxf(mx, 1e-30f);
      for (int k = 0; k < N; ++k) vv[k] *= inv;
    }
  }
  __syncthreads();

  // ---- MGS orthonormalization (block-parallel) ----
  for (int j = 0; j < RR; ++j) {
    for (int i2 = 0; i2 < j; ++i2) {
      float p_ = 0.f;
      { int k = tid; if (k < N) p_ = S.vt[i2][k] * S.vt[j][k]; }
      float dp = blkReduceSum(p_, S.red, tid);
      { int k = tid; if (k < N) S.vt[j][k] -= dp * S.vt[i2][k]; }
    }
    float p_ = 0.f;
    { int k = tid; if (k < N) p_ = S.vt[j][k] * S.vt[j][k]; }
    float nn = blkReduceSum(p_, S.red, tid);
    float inv = rsqrtf(fmaxf(nn, 1e-33f));
    { int k = tid; if (k < N) S.vt[j][k] *= inv; }
    __syncthreads();
  }

  // ---- back-transform: v = H_0 ... H_{N-3} v; u from ApkL * scl ----
  for (int vec = wv; vec < RR; vec += EIG_WAVES) {
    float* v = &S.vt[vec][0];
    for (int h = N - 3; h >= 0; --h) {
      const float sh = S.scls[h];
      float dp = 0.f;
      for (int k = lane; k < N; k += 64) {
        float uk = (k <= h) ? 0.f : ((k == h + 1) ? 1.f : S.ApkL[((k * (k - 1)) >> 1) + h] * sh);
        dp += uk * v[k];
      }
#pragma unroll
      for (int off = 32; off > 0; off >>= 1) dp += __shfl_down(dp, off, 64);
      dp = __shfl(dp, 0, 64);
      float c = S.taus[h] * dp;
      for (int k = lane; k < N; k += 64) {
        float uk = (k <= h) ? 0.f : ((k == h + 1) ? 1.f : S.ApkL[((k * (k - 1)) >> 1) + h] * sh);
        v[k] -= c * uk;
      }
    }
  }
  __syncthreads();

  // ---- canonical sign (max-|component| positive) + write F (N x RR) ----
  for (int vec = wv; vec < RR; vec += EIG_WAVES) {
    float* v = &S.vt[vec][0];
    float ma = -1.f; int mi = 0x7fffffff;
    for (int k = lane; k < N; k += 64) {
      float a = fabsf(v[k]);
      if (a > ma || (a == ma && k < mi)) { ma = a; mi = k; }
    }
#pragma unroll
    for (int off = 32; off > 0; off >>= 1) {
      float oa = __shfl_down(ma, off, 64);
      int oi = __shfl_down(mi, off, 64);
      if (oa > ma || (oa == ma && oi < mi)) { ma = oa; mi = oi; }
    }
    mi = __shfl(mi, 0, 64);
    float sg = (v[mi] < 0.f) ? -1.f : 1.f;
    for (int k = lane; k < N; k += 64) F[k * RR + vec] = sg * v[k];
  }
}

__global__ __launch_bounds__(EIG_THREADS, 1)
void keigh_init(const float* G0, float* F0, const float* G1, float* F1,
                const float* G2, float* F2, const float* G3, float* F3) {
  __shared__ ESm S;
  if (blockIdx.x == 0)      eig_body<32, 8>(S, G0, F0);
  else if (blockIdx.x == 1) eig_body<100, 6>(S, G1, F1);
  else if (blockIdx.x == 2) eig_body<128, 6>(S, G2, F2);
  else                      eig_body<64, 6>(S, G3, F3);
}

template<int N, int RR>
__global__ __launch_bounds__(EIG_THREADS, 1)
void keigh_one(const float* __restrict__ G, float* __restrict__ F) {
  __shared__ ESm S;
  eig_body<N, RR>(S, G, F);
}

// ---------------------------------------------------------------------------
extern "C" void kernel_launch(void* const* d_in, const int* in_sizes, int n_in,
                              void* d_out, int out_size, void* d_ws, size_t ws_size,
                              hipStream_t stream) {
  (void)in_sizes; (void)n_in; (void)out_size; (void)ws_size;
  const float* x  = (const float*)d_in[0];
  const float* cw = (const float*)d_in[1];
  const float* cb = (const float*)d_in[2];
  float* out = (float*)d_out;
  float* ws  = (float*)d_ws;

  float* T    = ws + OFF_T;
  float* TC   = ws + OFF_TC;
  float* TB   = ws + OFF_TB;
  float* PART = ws + OFF_PART;
  float* TD0a = ws + OFF_TD0a;
  float* TD0b = ws + OFF_TD0b;
  float* TD   = ws + OFF_TD;
  float* G0   = ws + OFF_G0;
  float* G1   = ws + OFF_G1;
  float* G2   = ws + OFF_G2;
  float* G3   = ws + OFF_G3;
  float* F0   = ws + OFF_F0;
  float* F1   = ws + OFF_F1;
  float* F2   = ws + OFF_F2;
  float* F3   = ws + OFF_F3;

  kconv<<<(26214400 + 255) / 256, 256, 0, stream>>>(x, cw, cb, T);

  // ---- HOSVD init: 4 grams, then one batched 4-block eigh ----
  kgram_big<32, false><<<120, 256, 0, stream>>>(T, PART, 1, 819200);
  kreduce<<<4, 256, 0, stream>>>(PART, G0, 1024);
  kgram_big<100, false><<<120, 256, 0, stream>>>(T, PART, 32, 8192);
  kreduce<<<40, 256, 0, stream>>>(PART, G1, 10000);
  kgram_big<128, false><<<120, 256, 0, stream>>>(T, PART, 3200, 64);
  kreduce<<<64, 256, 0, stream>>>(PART, G2, 16384);
  kgram_big<64, true><<<120, 256, 0, stream>>>(T, PART, 409600, 1);
  kreduce<<<16, 256, 0, stream>>>(PART, G3, 4096);

  keigh_init<<<4, EIG_THREADS, 0, stream>>>(G0, F0, G1, F1, G2, F2, G3, F3);

  // ---- HOOI sweeps ----
  for (int sweep = 0; sweep < 5; ++sweep) {
    // mode 0: Y = T x1 F1 x2 F2 x3 F3 -> (32,6,6,6)
    kcontract<6><<<1024, 256, 0, stream>>>(T, F1, TB, 32, 100, 8192);
    kcontract<6><<<48, 256, 0, stream>>>(TB, F2, TD0a, 192, 128, 64);
    kcontract<6><<<5, 256, 0, stream>>>(TD0a, F3, TD0b, 1152, 64, 1);
    kgram_small<<<4, 256, 0, stream>>>(TD0b, G0, 1, 32, 216);
    keigh_one<32, 8><<<1, EIG_THREADS, 0, stream>>>(G0, F0);
    // TC = T x0 F0 (reused by modes 1,2,3 and the final core)
    kcontract<8><<<3200, 256, 0, stream>>>(T, F0, TC, 1, 32, 819200);
    // mode 1
    kcontract<6><<<200, 256, 0, stream>>>(TC, F2, TB, 800, 128, 64);
    kcontract<6><<<19, 256, 0, stream>>>(TB, F3, TD, 4800, 64, 1);
    kgram_small<<<40, 256, 0, stream>>>(TD, G0, 8, 100, 36);
    keigh_one<100, 6><<<1, EIG_THREADS, 0, stream>>>(G0, F1);
    // mode 2 (TB = TC x1 F1 also reused by mode 3)
    kcontract<6><<<256, 256, 0, stream>>>(TC, F1, TB, 8, 100, 8192);
    kcontract<6><<<24, 256, 0, stream>>>(TB, F3, TD, 6144, 64, 1);
    kgram_small<<<64, 256, 0, stream>>>(TD, G0, 48, 128, 6);
    keigh_one<128, 6><<<1, EIG_THREADS, 0, stream>>>(G0, F2);
    // mode 3 (reuses TB from mode 2)
    kcontract<6><<<12, 256, 0, stream>>>(TB, F2, TD, 48, 128, 64);
    kgram_small<<<16, 256, 0, stream>>>(TD, G0, 288, 64, 1);
    keigh_one<64, 6><<<1, EIG_THREADS, 0, stream>>>(G0, F3);
  }

  // ---- core = (TC) x1 F1 x2 F2 x3 F3 -> (8,6,6,6) ----
  kcontract<6><<<256, 256, 0, stream>>>(TC, F1, TB, 8, 100, 8192);
  kcontract<6><<<12, 256, 0, stream>>>(TB, F2, TD, 48, 128, 64);
  kcontract<6><<<2, 256, 0, stream>>>(TD, F3, out, 288, 64, 1);
}

// Round 5
// 13246.709 us; speedup vs baseline: 1.7967x; 1.4126x over previous
//
#include <hip/hip_runtime.h>
#include <math.h>

// ---------------------------------------------------------------------------
// TensorProcessor: conv3d(1,3,1)+bias+relu -> Tucker-HOOI core (8,6,6,6)
// Round 5: eigh tridiagonalization with 2-thread row split (<=64 floats/thread)
// and explicitly batched float4 LDS broadcast reads (kills the per-element
// ds_read->wait->fma latency chain diagnosed in R3/R4). Householder math,
// multisection, invit, MGS, back-transform, canonical sign unchanged.
// ---------------------------------------------------------------------------

// ws layout (float offsets)
constexpr long long OFF_T   = 0LL;                 // 26,214,400
constexpr long long OFF_TC  = 26214400LL;          // 6,553,600
constexpr long long OFF_TB  = 32768000LL;          // 1,572,864
constexpr long long OFF_PART= OFF_TC;              // 120*16384 (init only)
constexpr long long OFF_TD0a= OFF_TC;              // mode0 (32,6,6,64)=73,728
constexpr long long OFF_TD0b= OFF_TC + 131072;     // mode0 (32,6,6,6)=6,912
constexpr long long OFF_TD  = OFF_TB + 1000000LL;  // sweep small tensors
constexpr long long OFF_G0  = OFF_TB + 1400000LL;  // 1,024
constexpr long long OFF_G1  = OFF_G0 + 1024;       // 10,000
constexpr long long OFF_G2  = OFF_G1 + 10000;      // 16,384
constexpr long long OFF_G3  = OFF_G2 + 16384;      // 4,096
constexpr long long OFF_F0  = 34340864LL;          // 256
constexpr long long OFF_F1  = OFF_F0 + 256;        // 600
constexpr long long OFF_F2  = OFF_F1 + 600;        // 768
constexpr long long OFF_F3  = OFF_F2 + 768;        // 384

// ---------------- conv + relu ----------------
__global__ void kconv(const float* __restrict__ x, const float* __restrict__ cw,
                      const float* __restrict__ cb, float* __restrict__ t) {
  int idx = blockIdx.x * blockDim.x + threadIdx.x;
  if (idx >= 26214400) return;
  int w  = idx & 63;
  int h  = (idx >> 6) & 127;
  int d  = (idx >> 13) % 100;
  int o  = idx / 819200;
  float acc = cb[o];
#pragma unroll
  for (int i = 0; i < 4; ++i) {
    const float* xi = x + (((long long)i * 100 + d) * 130 + h) * 64 + w;
#pragma unroll
    for (int kh = 0; kh < 3; ++kh)
      acc = fmaf(cw[(o * 4 + i) * 3 + kh], xi[kh * 64], acc);
  }
  t[idx] = fmaxf(acc, 0.f);
}

// ---------------- big gram (init HOSVD): G = X X^T over fibers ----------------
template<int D, bool TRANS>
__global__ void kgram_big(const float* __restrict__ T, float* __restrict__ part,
                          int P, long long Q) {
  constexpr int C = 64;
  constexpr int SUB = (D + 63) / 64;
  constexpr int DP = SUB * 64;
  __shared__ float tile[DP * (C + 1)];
  const int tid = threadIdx.x;                 // 256
  const int ta = tid >> 4, tb = tid & 15;
  float acc[SUB][SUB][4][4];
#pragma unroll
  for (int a = 0; a < SUB; ++a)
#pragma unroll
    for (int b = 0; b < SUB; ++b)
#pragma unroll
      for (int i = 0; i < 4; ++i)
#pragma unroll
        for (int j = 0; j < 4; ++j) acc[a][b][i][j] = 0.f;

  const long long nfib = (long long)P * Q;
  const int nchunk = (int)(nfib / C);
  for (int ch = blockIdx.x; ch < nchunk; ch += gridDim.x) {
    const long long base = (long long)ch * C;
    __syncthreads();
    if (TRANS) {
      for (int e = tid; e < D * C; e += 256) {
        int a = e & 63, cc = e >> 6;
        tile[a * (C + 1) + cc] = T[base * D + e];
      }
    } else {
      for (int e = tid; e < DP * C; e += 256) {
        int a = e / C, cc = e % C;
        float v = 0.f;
        if (a < D) {
          long long f = base + cc;
          long long p = f / Q, q = f - p * Q;
          v = T[(p * D + a) * Q + q];
        }
        tile[a * (C + 1) + cc] = v;
      }
    }
    __syncthreads();
    for (int cc = 0; cc < C; ++cc) {
      float av[SUB][4], bv[SUB][4];
#pragma unroll
      for (int si = 0; si < SUB; ++si)
#pragma unroll
        for (int i = 0; i < 4; ++i) av[si][i] = tile[(si * 64 + ta * 4 + i) * (C + 1) + cc];
#pragma unroll
      for (int sj = 0; sj < SUB; ++sj)
#pragma unroll
        for (int j = 0; j < 4; ++j) bv[sj][j] = tile[(sj * 64 + tb * 4 + j) * (C + 1) + cc];
#pragma unroll
      for (int si = 0; si < SUB; ++si)
#pragma unroll
        for (int sj = 0; sj < SUB; ++sj)
#pragma unroll
          for (int i = 0; i < 4; ++i)
#pragma unroll
            for (int j = 0; j < 4; ++j)
              acc[si][sj][i][j] = fmaf(av[si][i], bv[sj][j], acc[si][sj][i][j]);
    }
  }
  float* pb = part + (long long)blockIdx.x * D * D;
  for (int si = 0; si < SUB; ++si)
    for (int i = 0; i < 4; ++i) {
      int a = si * 64 + ta * 4 + i;
      if (a >= D) continue;
      for (int sj = 0; sj < SUB; ++sj)
        for (int j = 0; j < 4; ++j) {
          int b = sj * 64 + tb * 4 + j;
          if (b >= D) continue;
          pb[a * D + b] = acc[si][sj][i][j];
        }
    }
}

__global__ void kreduce(const float* __restrict__ part, float* __restrict__ G, int DD) {
  int i = blockIdx.x * blockDim.x + threadIdx.x;
  if (i >= DD) return;
  float s = 0.f;
  for (int b = 0; b < 120; ++b) s += part[(long long)b * DD + i];
  G[i] = s;
}

// ---------------- small gram (projected Y) ----------------
__global__ void kgram_small(const float* __restrict__ Y, float* __restrict__ G,
                            int P, int d, int Q) {
  int pair = blockIdx.x * blockDim.x + threadIdx.x;
  if (pair >= d * d) return;
  int a = pair / d, b = pair % d;
  float s = 0.f;
  for (int p = 0; p < P; ++p) {
    const float* ya = Y + ((long long)p * d + a) * Q;
    const float* yb = Y + ((long long)p * d + b) * Q;
    for (int q = 0; q < Q; ++q) s = fmaf(ya[q], yb[q], s);
  }
  G[pair] = s;
}

// ---------------- mode contraction: out[p,j,q] = sum_a F[a,j] in[p,a,q] ----------------
template<int R>
__global__ void kcontract(const float* __restrict__ in, const float* __restrict__ F,
                          float* __restrict__ out, int P, int d, long long Q) {
  long long total = (long long)P * Q;
  long long idx = (long long)blockIdx.x * blockDim.x + threadIdx.x;
  if (idx >= total) return;
  long long p = idx / Q, q = idx - p * Q;
  float acc[R];
#pragma unroll
  for (int j = 0; j < R; ++j) acc[j] = 0.f;
  const float* ip = in + (p * d) * Q + q;
  for (int a = 0; a < d; ++a) {
    float v = ip[(long long)a * Q];
#pragma unroll
    for (int j = 0; j < R; ++j) acc[j] = fmaf(F[a * R + j], v, acc[j]);
  }
  float* op = out + (p * R) * Q + q;
#pragma unroll
  for (int j = 0; j < R; ++j) op[(long long)j * Q] = acc[j];
}

// ---------------- eigh: top-r eigenvectors of symmetric G (n<=128) ----------------
#define EIG_THREADS 256
#define EIG_WAVES 4

struct __align__(16) ESm {
  float ApkL[8256];              // packed-lower Householder columns (export)
  float dd[128], ee[128], e2s[128];
  float colbuf[128];             // current pivot column
  float uu[128];                 // Householder vector u
  float wwf[128];                // final w vector
  float spp[256];                // symv half-partials [half*NP + row]
  float taus[128], scls[128];
  float vt[8][129];
  float slv[8][385];
  float lam[8];
  float red[EIG_WAVES];
  float sca[4];
};

// reduce WITHOUT entry barrier (caller guarantees arg-LDS already synced)
__device__ __forceinline__ float blkReduceSumNB(float v, volatile float* red, int tid) {
#pragma unroll
  for (int off = 32; off > 0; off >>= 1) v += __shfl_down(v, off, 64);
  if ((tid & 63) == 0) red[tid >> 6] = v;
  __syncthreads();
  float s = 0.f;
#pragma unroll
  for (int w = 0; w < EIG_WAVES; ++w) s += red[w];
  return s;
}

__device__ __forceinline__ float blkReduceSum(float v, volatile float* red, int tid) {
  __syncthreads();
  return blkReduceSumNB(v, red, tid);
}

template<int N, int RR>
__device__ void eig_body(ESm& S, const float* __restrict__ G, float* __restrict__ F) {
  constexpr int NP = (N <= 32) ? 32 : ((N <= 64) ? 64 : 128);
  constexpr int HL = NP / 2;           // elements per half-row (<= 64)
  constexpr int NC = HL / 4;           // float4 chunks per half (<= 16)
  const int tid = threadIdx.x;
  const int lane = tid & 63, wv = tid >> 6;
  const int row  = tid & (NP - 1);
  const int half = tid / NP;           // NP is pow2 -> shift
  const bool hact = (half < 2);
  const bool act  = hact && (row < N);
  const int l0 = (half < 2 ? half : 0) * HL;
  const int lcount = (half == 0) ? HL : (N - HL);

  const float4* uu4 = (const float4*)S.uu;
  const float4* ww4 = (const float4*)S.wwf;

  // ---- load: thread (row, half) owns elements [l0, l0+lcount) of row ----
  float Ar[HL];
#pragma unroll
  for (int j = 0; j < HL; ++j) Ar[j] = 0.f;
  if (act) {
#pragma unroll
    for (int j = 0; j < HL; ++j)
      if (j < lcount) Ar[j] = G[row * N + l0 + j];
  }
  // colbuf <- column 0 = row 0 (pad region stays exactly 0)
  if (hact && row == 0) {
    float4* cb4 = (float4*)S.colbuf;
#pragma unroll
    for (int c = 0; c < NC; ++c)
      cb4[half * NC + c] = make_float4(Ar[4 * c], Ar[4 * c + 1], Ar[4 * c + 2], Ar[4 * c + 3]);
  }

  // ---- Householder tridiagonalization (LAPACK slarfg conventions) ----
  for (int i = 0; i <= N - 3; ++i) {
    __syncthreads();                                   // B1: colbuf/uu/wwf of prev step visible
    float prt = 0.f;
    { int k2 = i + 2 + tid; if (k2 < N) { float v = S.colbuf[k2]; prt = v * v; } }
    float xnorm2 = blkReduceSumNB(prt, S.red, tid);    // B2 internal
    float alpha = S.colbuf[i + 1];
    float beta, tau_i, scl_i;
    if (xnorm2 == 0.f) { beta = alpha; tau_i = 0.f; scl_i = 0.f; }
    else {
      float an = sqrtf(alpha * alpha + xnorm2);
      beta = (alpha >= 0.f) ? -an : an;
      tau_i = (beta - alpha) / beta;
      scl_i = 1.f / (alpha - beta);
    }
    // u for my row (same expression as the uu[] entries)
    float u_row = 0.f;
    if (act) {
      if (row == i + 1) u_row = 1.f;
      else if (row >= i + 2) u_row = S.colbuf[row] * scl_i;
    }
    if (half == 0) S.uu[row] = u_row;                  // rows >= N write 0 (pad exact)
    __syncthreads();                                   // B3: uu visible
    // symv half: batched float4 broadcast loads, then fma chain
    float s = 0.f;
    if (hact) {
      float4 ub[NC];
#pragma unroll
      for (int c = 0; c < NC; ++c) ub[c] = uu4[half * NC + c];
#pragma unroll
      for (int c = 0; c < NC; ++c) {
        s = fmaf(Ar[4 * c + 0], ub[c].x, s);
        s = fmaf(Ar[4 * c + 1], ub[c].y, s);
        s = fmaf(Ar[4 * c + 2], ub[c].z, s);
        s = fmaf(Ar[4 * c + 3], ub[c].w, s);
      }
      S.spp[half * NP + row] = s;
    }
    __syncthreads();                                   // B4: spp visible
    float w_pre = 0.f;
    if (hact) {
      float s_full = S.spp[row] + S.spp[NP + row];
      if (act && row >= i + 1) w_pre = tau_i * s_full;
    }
    float p2 = (half == 0) ? w_pre * u_row : 0.f;      // u_row=0 for row<=i: exact gate
    float pu = blkReduceSumNB(p2, S.red, tid);         // B5 internal
    float halfc = -0.5f * tau_i * pu;
    float w_fin = w_pre + halfc * u_row;
    if (half == 0) S.wwf[row] = w_fin;                 // rows >= N write 0
    __syncthreads();                                   // B6: wwf visible
    // trailing update: Ar[l] -= u_row*w_l + w_fin*u_l (symmetric-exact form)
    if (hact) {
      float4 ub[NC], wb[NC];
#pragma unroll
      for (int c = 0; c < NC; ++c) { ub[c] = uu4[half * NC + c]; wb[c] = ww4[half * NC + c]; }
#pragma unroll
      for (int c = 0; c < NC; ++c) {
        Ar[4 * c + 0] -= __fadd_rn(__fmul_rn(u_row, wb[c].x), __fmul_rn(w_fin, ub[c].x));
        Ar[4 * c + 1] -= __fadd_rn(__fmul_rn(u_row, wb[c].y), __fmul_rn(w_fin, ub[c].y));
        Ar[4 * c + 2] -= __fadd_rn(__fmul_rn(u_row, wb[c].z), __fmul_rn(w_fin, ub[c].z));
        Ar[4 * c + 3] -= __fadd_rn(__fmul_rn(u_row, wb[c].w), __fmul_rn(w_fin, ub[c].w));
      }
      if (row == i + 1) {                              // next step's pivot column = my row
        float4* cb4 = (float4*)S.colbuf;
#pragma unroll
        for (int c = 0; c < NC; ++c)
          cb4[half * NC + c] = make_float4(Ar[4 * c], Ar[4 * c + 1], Ar[4 * c + 2], Ar[4 * c + 3]);
      }
    }
    if (tid == 0) { S.ee[i] = beta; S.taus[i] = tau_i; S.scls[i] = scl_i; }
  }
  __syncthreads();

  // ---- export diag + packed-lower Householder columns to LDS ----
  if (act) {
    if (row >= l0 && row < l0 + HL) {
      float dv = 0.f;
#pragma unroll
      for (int j = 0; j < HL; ++j) if (l0 + j == row) dv = Ar[j];
      S.dd[row] = dv;
    }
    int base = (row * (row - 1)) >> 1;
#pragma unroll
    for (int j = 0; j < HL; ++j) {
      int h = l0 + j;
      if (h < row) S.ApkL[base + h] = Ar[j];
    }
  }
  if (half == 1 && row == N - 1) S.ee[N - 2] = Ar[N - 2 - HL];
  __syncthreads();
  if (tid < N) S.e2s[tid] = (tid >= 1) ? S.ee[tid - 1] * S.ee[tid - 1] : 0.f;

  // ---- Gershgorin bounds + pivmin ----
  if (tid == 0) {
    float lo = 3.4e38f, hi = -3.4e38f, me2 = 0.f;
    for (int ii = 0; ii < N; ++ii) {
      float rad = 0.f;
      if (ii > 0) rad += fabsf(S.ee[ii - 1]);
      if (ii < N - 1) { rad += fabsf(S.ee[ii]); me2 = fmaxf(me2, S.ee[ii] * S.ee[ii]); }
      lo = fminf(lo, S.dd[ii] - rad);
      hi = fmaxf(hi, S.dd[ii] + rad);
    }
    float span = hi - lo;
    S.sca[0] = lo - 0.001f * span - 1e-20f;
    S.sca[1] = hi + 0.001f * span + 1e-20f;
    S.sca[2] = 1.1754944e-38f * fmaxf(1.f, me2);
  }
  __syncthreads();
  const float pivmin = S.sca[2];

  // ---- 33-way multisection: 32 threads per eigenvalue, 8 rounds ----
  {
    const int grp = tid >> 5, gt = tid & 31;
    if (grp < RR) {
      const int krank = N - 1 - grp;
      float lo = S.sca[0], hi = S.sca[1];
      for (int round = 0; round < 8; ++round) {
        float w = (hi - lo) * (1.f / 33.f);
        float sg = fmaf(w, (float)(gt + 1), lo);
        int cnt = 0;
        float q = S.dd[0] - sg;
        if (q < 0.f) cnt++;
        for (int ii = 1; ii < N; ++ii) {
          if (fabsf(q) < pivmin) q = -pivmin;
          q = S.dd[ii] - sg - S.e2s[ii] / q;
          if (q < 0.f) cnt++;
        }
        float nlo = (cnt <= krank) ? sg : lo;
        float nhi = (cnt >  krank) ? sg : hi;
#pragma unroll
        for (int off = 16; off > 0; off >>= 1) {
          nlo = fmaxf(nlo, __shfl_down(nlo, off, 32));
          nhi = fminf(nhi, __shfl_down(nhi, off, 32));
        }
        nlo = __shfl(nlo, 0, 32);
        nhi = __shfl(nhi, 0, 32);
        lo = fminf(nlo, nhi); hi = fmaxf(nlo, nhi);
      }
      if (gt == 0) S.lam[grp] = 0.5f * (lo + hi) * (1.f + (float)grp * 3e-7f);
    }
  }
  __syncthreads();

  // ---- inverse iteration, register-carried recurrence ----
  if (tid < RR) {
    const int j = tid;
    float* u0 = &S.slv[j][0];
    float* u1 = &S.slv[j][128];
    float* u2 = &S.slv[j][256];
    float* vv = &S.vt[j][0];
    const float lj = S.lam[j];
    for (int k = 0; k < N; ++k) vv[k] = 1.f;
    for (int itr = 0; itr < 3; ++itr) {
      float d = S.dd[0] - lj;
      float e = S.ee[0];
      float cv = vv[0];
      for (int i = 0; i < N - 1; ++i) {
        float bi = S.ee[i];
        float d1 = S.dd[i + 1] - lj;
        float e1 = (i + 1 < N - 1) ? S.ee[i + 1] : 0.f;
        float vnext = vv[i + 1];
        float ai = d, ci = e;
        if (fabsf(ai) >= fabsf(bi)) {
          if (fabsf(ai) < pivmin) ai = (ai >= 0.f ? pivmin : -pivmin);
          float m = bi / ai;
          u0[i] = ai; u1[i] = ci; u2[i] = 0.f;
          d = d1 - m * ci;
          e = e1;
          vv[i] = cv;
          cv = vnext - m * cv;
        } else {
          float m = ai / bi;
          u0[i] = bi; u1[i] = d1; u2[i] = e1;
          d = ci - m * d1;
          e = -m * e1;
          vv[i] = vnext;
          cv = cv - m * vnext;
        }
      }
      if (fabsf(d) < pivmin) d = (d >= 0.f ? pivmin : -pivmin);
      float vi2 = cv / d;
      vv[N - 1] = vi2;
      float vi1 = (vv[N - 2] - u1[N - 2] * vi2) / u0[N - 2];
      vv[N - 2] = vi1;
      for (int i = N - 3; i >= 0; --i) {
        float t = (vv[i] - u1[i] * vi1 - u2[i] * vi2) / u0[i];
        vv[i] = t;
        vi2 = vi1; vi1 = t;
      }
      float mx = 0.f;
      for (int k = 0; k < N; ++k) mx = fmaxf(mx, fabsf(vv[k]));
      float inv = 1.f / fmaxf(mx, 1e-30f);
      for (int k = 0; k < N; ++k) vv[k] *= inv;
    }
  }
  __syncthreads();

  // ---- MGS orthonormalization (block-parallel) ----
  for (int j = 0; j < RR; ++j) {
    for (int i2 = 0; i2 < j; ++i2) {
      float p_ = 0.f;
      { int k = tid; if (k < N) p_ = S.vt[i2][k] * S.vt[j][k]; }
      float dp = blkReduceSum(p_, S.red, tid);
      { int k = tid; if (k < N) S.vt[j][k] -= dp * S.vt[i2][k]; }
    }
    float p_ = 0.f;
    { int k = tid; if (k < N) p_ = S.vt[j][k] * S.vt[j][k]; }
    float nn = blkReduceSum(p_, S.red, tid);
    float inv = rsqrtf(fmaxf(nn, 1e-33f));
    { int k = tid; if (k < N) S.vt[j][k] *= inv; }
    __syncthreads();
  }

  // ---- back-transform: v = H_0 ... H_{N-3} v; u from ApkL * scl ----
  for (int vec = wv; vec < RR; vec += EIG_WAVES) {
    float* v = &S.vt[vec][0];
    for (int h = N - 3; h >= 0; --h) {
      const float sh = S.scls[h];
      float dp = 0.f;
      for (int k = lane; k < N; k += 64) {
        float uk = (k <= h) ? 0.f : ((k == h + 1) ? 1.f : S.ApkL[((k * (k - 1)) >> 1) + h] * sh);
        dp += uk * v[k];
      }
#pragma unroll
      for (int off = 32; off > 0; off >>= 1) dp += __shfl_down(dp, off, 64);
      dp = __shfl(dp, 0, 64);
      float c = S.taus[h] * dp;
      for (int k = lane; k < N; k += 64) {
        float uk = (k <= h) ? 0.f : ((k == h + 1) ? 1.f : S.ApkL[((k * (k - 1)) >> 1) + h] * sh);
        v[k] -= c * uk;
      }
    }
  }
  __syncthreads();

  // ---- canonical sign (max-|component| positive) + write F (N x RR) ----
  for (int vec = wv; vec < RR; vec += EIG_WAVES) {
    float* v = &S.vt[vec][0];
    float ma = -1.f; int mi = 0x7fffffff;
    for (int k = lane; k < N; k += 64) {
      float a = fabsf(v[k]);
      if (a > ma || (a == ma && k < mi)) { ma = a; mi = k; }
    }
#pragma unroll
    for (int off = 32; off > 0; off >>= 1) {
      float oa = __shfl_down(ma, off, 64);
      int oi = __shfl_down(mi, off, 64);
      if (oa > ma || (oa == ma && oi < mi)) { ma = oa; mi = oi; }
    }
    mi = __shfl(mi, 0, 64);
    float sg = (v[mi] < 0.f) ? -1.f : 1.f;
    for (int k = lane; k < N; k += 64) F[k * RR + vec] = sg * v[k];
  }
}

__global__ __launch_bounds__(EIG_THREADS, 1)
void keigh_init(const float* G0, float* F0, const float* G1, float* F1,
                const float* G2, float* F2, const float* G3, float* F3) {
  __shared__ ESm S;
  if (blockIdx.x == 0)      eig_body<32, 8>(S, G0, F0);
  else if (blockIdx.x == 1) eig_body<100, 6>(S, G1, F1);
  else if (blockIdx.x == 2) eig_body<128, 6>(S, G2, F2);
  else                      eig_body<64, 6>(S, G3, F3);
}

template<int N, int RR>
__global__ __launch_bounds__(EIG_THREADS, 1)
void keigh_one(const float* __restrict__ G, float* __restrict__ F) {
  __shared__ ESm S;
  eig_body<N, RR>(S, G, F);
}

// ---------------------------------------------------------------------------
extern "C" void kernel_launch(void* const* d_in, const int* in_sizes, int n_in,
                              void* d_out, int out_size, void* d_ws, size_t ws_size,
                              hipStream_t stream) {
  (void)in_sizes; (void)n_in; (void)out_size; (void)ws_size;
  const float* x  = (const float*)d_in[0];
  const float* cw = (const float*)d_in[1];
  const float* cb = (const float*)d_in[2];
  float* out = (float*)d_out;
  float* ws  = (float*)d_ws;

  float* T    = ws + OFF_T;
  float* TC   = ws + OFF_TC;
  float* TB   = ws + OFF_TB;
  float* PART = ws + OFF_PART;
  float* TD0a = ws + OFF_TD0a;
  float* TD0b = ws + OFF_TD0b;
  float* TD   = ws + OFF_TD;
  float* G0   = ws + OFF_G0;
  float* G1   = ws + OFF_G1;
  float* G2   = ws + OFF_G2;
  float* G3   = ws + OFF_G3;
  float* F0   = ws + OFF_F0;
  float* F1   = ws + OFF_F1;
  float* F2   = ws + OFF_F2;
  float* F3   = ws + OFF_F3;

  kconv<<<(26214400 + 255) / 256, 256, 0, stream>>>(x, cw, cb, T);

  // ---- HOSVD init: 4 grams, then one batched 4-block eigh ----
  kgram_big<32, false><<<120, 256, 0, stream>>>(T, PART, 1, 819200);
  kreduce<<<4, 256, 0, stream>>>(PART, G0, 1024);
  kgram_big<100, false><<<120, 256, 0, stream>>>(T, PART, 32, 8192);
  kreduce<<<40, 256, 0, stream>>>(PART, G1, 10000);
  kgram_big<128, false><<<120, 256, 0, stream>>>(T, PART, 3200, 64);
  kreduce<<<64, 256, 0, stream>>>(PART, G2, 16384);
  kgram_big<64, true><<<120, 256, 0, stream>>>(T, PART, 409600, 1);
  kreduce<<<16, 256, 0, stream>>>(PART, G3, 4096);

  keigh_init<<<4, EIG_THREADS, 0, stream>>>(G0, F0, G1, F1, G2, F2, G3, F3);

  // ---- HOOI sweeps ----
  for (int sweep = 0; sweep < 5; ++sweep) {
    // mode 0: Y = T x1 F1 x2 F2 x3 F3 -> (32,6,6,6)
    kcontract<6><<<1024, 256, 0, stream>>>(T, F1, TB, 32, 100, 8192);
    kcontract<6><<<48, 256, 0, stream>>>(TB, F2, TD0a, 192, 128, 64);
    kcontract<6><<<5, 256, 0, stream>>>(TD0a, F3, TD0b, 1152, 64, 1);
    kgram_small<<<4, 256, 0, stream>>>(TD0b, G0, 1, 32, 216);
    keigh_one<32, 8><<<1, EIG_THREADS, 0, stream>>>(G0, F0);
    // TC = T x0 F0 (reused by modes 1,2,3 and the final core)
    kcontract<8><<<3200, 256, 0, stream>>>(T, F0, TC, 1, 32, 819200);
    // mode 1
    kcontract<6><<<200, 256, 0, stream>>>(TC, F2, TB, 800, 128, 64);
    kcontract<6><<<19, 256, 0, stream>>>(TB, F3, TD, 4800, 64, 1);
    kgram_small<<<40, 256, 0, stream>>>(TD, G0, 8, 100, 36);
    keigh_one<100, 6><<<1, EIG_THREADS, 0, stream>>>(G0, F1);
    // mode 2 (TB = TC x1 F1 also reused by mode 3)
    kcontract<6><<<256, 256, 0, stream>>>(TC, F1, TB, 8, 100, 8192);
    kcontract<6><<<24, 256, 0, stream>>>(TB, F3, TD, 6144, 64, 1);
    kgram_small<<<64, 256, 0, stream>>>(TD, G0, 48, 128, 6);
    keigh_one<128, 6><<<1, EIG_THREADS, 0, stream>>>(G0, F2);
    // mode 3 (reuses TB from mode 2)
    kcontract<6><<<12, 256, 0, stream>>>(TB, F2, TD, 48, 128, 64);
    kgram_small<<<16, 256, 0, stream>>>(TD, G0, 288, 64, 1);
    keigh_one<64, 6><<<1, EIG_THREADS, 0, stream>>>(G0, F3);
  }

  // ---- core = (TC) x1 F1 x2 F2 x3 F3 -> (8,6,6,6) ----
  kcontract<6><<<256, 256, 0, stream>>>(TC, F1, TB, 8, 100, 8192);
  kcontract<6><<<12, 256, 0, stream>>>(TB, F2, TD, 48, 128, 64);
  kcontract<6><<<2, 256, 0, stream>>>(TD, F3, out, 288, 64, 1);
}

// Round 6
// 12145.349 us; speedup vs baseline: 1.9596x; 1.0907x over previous
//
#include <hip/hip_runtime.h>
#include <math.h>

// ---------------------------------------------------------------------------
// TensorProcessor: conv3d(1,3,1)+bias+relu -> Tucker-HOOI core (8,6,6,6)
// Round 6: spill-free eigh tridiagonalization. 4-way row split (512 thr,
// thread (row,q) owns <=32 floats), u recomputed from in-register colbuf
// segment, w via one LDS round-trip consumed in small chunks. Multisection /
// invit / MGS / back-transform / canonical sign unchanged. kgram_big: 240
// blocks + compile-time Q; kcontract compile-time Q.
// ---------------------------------------------------------------------------

// ws layout (float offsets)
constexpr long long OFF_T   = 0LL;                 // 26,214,400
constexpr long long OFF_TC  = 26214400LL;          // 6,553,600
constexpr long long OFF_TB  = 32768000LL;          // 1,572,864
constexpr long long OFF_PART= OFF_TC;              // 240*16384 (init only)
constexpr long long OFF_TD0a= OFF_TC;              // mode0 (32,6,6,64)=73,728
constexpr long long OFF_TD0b= OFF_TC + 131072;     // mode0 (32,6,6,6)=6,912
constexpr long long OFF_TD  = OFF_TB + 1000000LL;  // sweep small tensors
constexpr long long OFF_G0  = OFF_TB + 1400000LL;  // 1,024
constexpr long long OFF_G1  = OFF_G0 + 1024;       // 10,000
constexpr long long OFF_G2  = OFF_G1 + 10000;      // 16,384
constexpr long long OFF_G3  = OFF_G2 + 16384;      // 4,096
constexpr long long OFF_F0  = 34340864LL;          // 256
constexpr long long OFF_F1  = OFF_F0 + 256;        // 600
constexpr long long OFF_F2  = OFF_F1 + 600;        // 768
constexpr long long OFF_F3  = OFF_F2 + 768;        // 384

// ---------------- conv + relu ----------------
__global__ void kconv(const float* __restrict__ x, const float* __restrict__ cw,
                      const float* __restrict__ cb, float* __restrict__ t) {
  int idx = blockIdx.x * blockDim.x + threadIdx.x;
  if (idx >= 26214400) return;
  int w  = idx & 63;
  int h  = (idx >> 6) & 127;
  int d  = (idx >> 13) % 100;
  int o  = idx / 819200;
  float acc = cb[o];
#pragma unroll
  for (int i = 0; i < 4; ++i) {
    const float* xi = x + (((long long)i * 100 + d) * 130 + h) * 64 + w;
#pragma unroll
    for (int kh = 0; kh < 3; ++kh)
      acc = fmaf(cw[(o * 4 + i) * 3 + kh], xi[kh * 64], acc);
  }
  t[idx] = fmaxf(acc, 0.f);
}

// ---------------- big gram (init HOSVD): G = X X^T over fibers ----------------
#define GRAM_BLOCKS 240
template<int D, long long QQ, bool TRANS>
__global__ void kgram_big(const float* __restrict__ T, float* __restrict__ part,
                          int P) {
  constexpr int C = 64;
  constexpr int SUB = (D + 63) / 64;
  constexpr int DP = SUB * 64;
  __shared__ float tile[DP * (C + 1)];
  const int tid = threadIdx.x;                 // 256
  const int ta = tid >> 4, tb = tid & 15;
  float acc[SUB][SUB][4][4];
#pragma unroll
  for (int a = 0; a < SUB; ++a)
#pragma unroll
    for (int b = 0; b < SUB; ++b)
#pragma unroll
      for (int i = 0; i < 4; ++i)
#pragma unroll
        for (int j = 0; j < 4; ++j) acc[a][b][i][j] = 0.f;

  const long long nfib = (long long)P * QQ;
  const int nchunk = (int)(nfib / C);
  for (int ch = blockIdx.x; ch < nchunk; ch += gridDim.x) {
    const long long base = (long long)ch * C;
    __syncthreads();
    if (TRANS) {
      for (int e = tid; e < D * C; e += 256) {
        int a = e & 63, cc = e >> 6;
        tile[a * (C + 1) + cc] = T[base * D + e];
      }
    } else {
      for (int e = tid; e < DP * C; e += 256) {
        int a = e / C, cc = e % C;
        float v = 0.f;
        if (a < D) {
          long long f = base + cc;
          long long p = f / QQ, q = f - p * QQ;   // compile-time QQ
          v = T[(p * D + a) * QQ + q];
        }
        tile[a * (C + 1) + cc] = v;
      }
    }
    __syncthreads();
    for (int cc = 0; cc < C; ++cc) {
      float av[SUB][4], bv[SUB][4];
#pragma unroll
      for (int si = 0; si < SUB; ++si)
#pragma unroll
        for (int i = 0; i < 4; ++i) av[si][i] = tile[(si * 64 + ta * 4 + i) * (C + 1) + cc];
#pragma unroll
      for (int sj = 0; sj < SUB; ++sj)
#pragma unroll
        for (int j = 0; j < 4; ++j) bv[sj][j] = tile[(sj * 64 + tb * 4 + j) * (C + 1) + cc];
#pragma unroll
      for (int si = 0; si < SUB; ++si)
#pragma unroll
        for (int sj = 0; sj < SUB; ++sj)
#pragma unroll
          for (int i = 0; i < 4; ++i)
#pragma unroll
            for (int j = 0; j < 4; ++j)
              acc[si][sj][i][j] = fmaf(av[si][i], bv[sj][j], acc[si][sj][i][j]);
    }
  }
  float* pb = part + (long long)blockIdx.x * D * D;
  for (int si = 0; si < SUB; ++si)
    for (int i = 0; i < 4; ++i) {
      int a = si * 64 + ta * 4 + i;
      if (a >= D) continue;
      for (int sj = 0; sj < SUB; ++sj)
        for (int j = 0; j < 4; ++j) {
          int b = sj * 64 + tb * 4 + j;
          if (b >= D) continue;
          pb[a * D + b] = acc[si][sj][i][j];
        }
    }
}

__global__ void kreduce(const float* __restrict__ part, float* __restrict__ G, int DD) {
  int i = blockIdx.x * blockDim.x + threadIdx.x;
  if (i >= DD) return;
  float s = 0.f;
  for (int b = 0; b < GRAM_BLOCKS; ++b) s += part[(long long)b * DD + i];
  G[i] = s;
}

// ---------------- small gram (projected Y) ----------------
__global__ void kgram_small(const float* __restrict__ Y, float* __restrict__ G,
                            int P, int d, int Q) {
  int pair = blockIdx.x * blockDim.x + threadIdx.x;
  if (pair >= d * d) return;
  int a = pair / d, b = pair % d;
  float s = 0.f;
  for (int p = 0; p < P; ++p) {
    const float* ya = Y + ((long long)p * d + a) * Q;
    const float* yb = Y + ((long long)p * d + b) * Q;
    for (int q = 0; q < Q; ++q) s = fmaf(ya[q], yb[q], s);
  }
  G[pair] = s;
}

// ---------------- mode contraction: out[p,j,q] = sum_a F[a,j] in[p,a,q] ----------------
template<int R, long long QV>
__global__ void kcontract(const float* __restrict__ in, const float* __restrict__ F,
                          float* __restrict__ out, int P, int d) {
  long long total = (long long)P * QV;
  long long idx = (long long)blockIdx.x * blockDim.x + threadIdx.x;
  if (idx >= total) return;
  long long p = idx / QV, q = idx - p * QV;
  float acc[R];
#pragma unroll
  for (int j = 0; j < R; ++j) acc[j] = 0.f;
  const float* ip = in + (p * d) * QV + q;
  for (int a = 0; a < d; ++a) {
    float v = ip[(long long)a * QV];
#pragma unroll
    for (int j = 0; j < R; ++j) acc[j] = fmaf(F[a * R + j], v, acc[j]);
  }
  float* op = out + (p * R) * QV + q;
#pragma unroll
  for (int j = 0; j < R; ++j) op[(long long)j * QV] = acc[j];
}

// ---------------- eigh: top-r eigenvectors of symmetric G (n<=128) ----------------
#define EIG_THREADS 512
#define EIG_WAVES 8

struct __align__(16) ESm {
  float ApkL[8256];              // packed-lower Householder columns (export)
  float colbuf[128];             // current pivot column (16B-aligned)
  float wwf[128];                // final w vector
  float spp[512];                // symv quarter-partials [row*4 + q]
  float dd[128], ee[128], e2s[128];
  float taus[128], scls[128];
  float vt[8][129];
  float slv[8][385];
  float lam[8];
  float red[EIG_WAVES];
  float sca[4];
};

// reduce WITHOUT entry barrier (caller guarantees arg-LDS already synced)
__device__ __forceinline__ float blkReduceSumNB(float v, volatile float* red, int tid) {
#pragma unroll
  for (int off = 32; off > 0; off >>= 1) v += __shfl_down(v, off, 64);
  if ((tid & 63) == 0) red[tid >> 6] = v;
  __syncthreads();
  float s = 0.f;
#pragma unroll
  for (int w = 0; w < EIG_WAVES; ++w) s += red[w];
  return s;
}

__device__ __forceinline__ float blkReduceSum(float v, volatile float* red, int tid) {
  __syncthreads();
  return blkReduceSumNB(v, red, tid);
}

template<int N, int RR>
__device__ void eig_body(ESm& S, const float* __restrict__ G, float* __restrict__ F) {
  constexpr int NP  = (N <= 32) ? 32 : ((N <= 64) ? 64 : 128);
  constexpr int QL  = NP / 4;          // floats per thread segment (8/16/32)
  constexpr int NC4 = QL / 4;          // float4 chunks per segment
  const int tid  = threadIdx.x;
  const int lane = tid & 63, wv = tid >> 6;
  const int row  = tid & (NP - 1);
  const int q    = tid / NP;           // pow2 -> shift
  const bool act4 = (q < 4);
  const bool act  = act4 && (row < N);
  const int l0 = (act4 ? q : 0) * QL;

  float4* cb4 = (float4*)S.colbuf;
  float4* ww4 = (float4*)S.wwf;
  float4* sp4 = (float4*)S.spp;

  // ---- load: thread (row,q) owns A[row][l0 .. l0+QL) in VGPRs ----
  float Ar[QL];
#pragma unroll
  for (int j = 0; j < QL; ++j) Ar[j] = 0.f;
  if (act) {
#pragma unroll
    for (int j = 0; j < QL; ++j) { int l = l0 + j; if (l < N) Ar[j] = G[row * N + l]; }
  }
  if (act4 && row == 0) {              // colbuf <- column 0 = row 0 (pads exact 0)
#pragma unroll
    for (int c = 0; c < NC4; ++c)
      cb4[(l0 >> 2) + c] = make_float4(Ar[4*c], Ar[4*c+1], Ar[4*c+2], Ar[4*c+3]);
  }

  // ---- Householder tridiagonalization (LAPACK slarfg conventions) ----
  for (int i = 0; i <= N - 3; ++i) {
    __syncthreads();                                   // B1: colbuf of prev step visible
    // batch-load my colbuf segment into registers
    float cbs[QL];
#pragma unroll
    for (int c = 0; c < NC4; ++c) {
      float4 t = cb4[(l0 >> 2) + c];
      cbs[4*c] = t.x; cbs[4*c+1] = t.y; cbs[4*c+2] = t.z; cbs[4*c+3] = t.w;
    }
    float prt = 0.f;
    if (act4 && row == 0) {                            // 4 threads: segment-wise norm
#pragma unroll
      for (int j = 0; j < QL; ++j) {
        int l = l0 + j;
        if (l >= i + 2) prt = fmaf(cbs[j], cbs[j], prt);
      }
    }
    float xnorm2 = blkReduceSumNB(prt, S.red, tid);    // B2 inside
    float alpha = S.colbuf[i + 1];
    float beta, tau_i, scl_i;
    if (xnorm2 == 0.f) { beta = alpha; tau_i = 0.f; scl_i = 0.f; }
    else {
      float an = sqrtf(alpha * alpha + xnorm2);
      beta = (alpha >= 0.f) ? -an : an;
      tau_i = (beta - alpha) / beta;
      scl_i = 1.f / (alpha - beta);
    }
    float u_row = 0.f;
    if (act) {
      if (row == i + 1) u_row = 1.f;
      else if (row >= i + 2) u_row = S.colbuf[row] * scl_i;
    }
    // symv: entirely from registers (u recomputed from cbs)
    float s = 0.f;
#pragma unroll
    for (int j = 0; j < QL; ++j) {
      int l = l0 + j;
      float u_l = (l == i + 1) ? 1.f : ((l >= i + 2) ? cbs[j] * scl_i : 0.f);
      s = fmaf(Ar[j], u_l, s);
    }
    if (act4) S.spp[row * 4 + q] = s;
    __syncthreads();                                   // B3: spp visible
    float4 sp = sp4[row];
    float s_full = ((sp.x + sp.y) + sp.z) + sp.w;
    float w_pre = (act && row >= i + 1) ? tau_i * s_full : 0.f;
    float p2 = (q == 0) ? w_pre * u_row : 0.f;
    float pu = blkReduceSumNB(p2, S.red, tid);         // B4 inside
    float halfc = -0.5f * tau_i * pu;
    float w_row = w_pre + halfc * u_row;
    if (q == 0) S.wwf[row] = w_row;                    // pad rows write exact 0
    __syncthreads();                                   // B5: wwf visible
    // trailing update: chunked w loads (low register pressure), symmetric-exact
    if (act4) {
#pragma unroll
      for (int c = 0; c < NC4; ++c) {
        float4 t = ww4[(l0 >> 2) + c];
        float wl[4] = {t.x, t.y, t.z, t.w};
#pragma unroll
        for (int jj = 0; jj < 4; ++jj) {
          int j = 4 * c + jj;
          int l = l0 + j;
          float u_l = (l == i + 1) ? 1.f : ((l >= i + 2) ? cbs[j] * scl_i : 0.f);
          Ar[j] -= __fadd_rn(__fmul_rn(u_row, wl[jj]), __fmul_rn(w_row, u_l));
        }
      }
      if (row == i + 1) {                              // next pivot column = my row
#pragma unroll
        for (int c = 0; c < NC4; ++c)
          cb4[(l0 >> 2) + c] = make_float4(Ar[4*c], Ar[4*c+1], Ar[4*c+2], Ar[4*c+3]);
      }
    }
    if (tid == 0) { S.ee[i] = beta; S.taus[i] = tau_i; S.scls[i] = scl_i; }
  }
  __syncthreads();

  // ---- export diag + packed-lower Householder columns + last off-diag ----
  if (act) {
    int base = (row * (row - 1)) >> 1;
#pragma unroll
    for (int j = 0; j < QL; ++j) {
      int l = l0 + j;
      if (l == row) S.dd[row] = Ar[j];
      if (l < row)  S.ApkL[base + l] = Ar[j];
      if (row == N - 1 && l == N - 2) S.ee[N - 2] = Ar[j];
    }
  }
  __syncthreads();
  if (tid < N) S.e2s[tid] = (tid >= 1) ? S.ee[tid - 1] * S.ee[tid - 1] : 0.f;

  // ---- Gershgorin bounds + pivmin ----
  if (tid == 0) {
    float lo = 3.4e38f, hi = -3.4e38f, me2 = 0.f;
    for (int ii = 0; ii < N; ++ii) {
      float rad = 0.f;
      if (ii > 0) rad += fabsf(S.ee[ii - 1]);
      if (ii < N - 1) { rad += fabsf(S.ee[ii]); me2 = fmaxf(me2, S.ee[ii] * S.ee[ii]); }
      lo = fminf(lo, S.dd[ii] - rad);
      hi = fmaxf(hi, S.dd[ii] + rad);
    }
    float span = hi - lo;
    S.sca[0] = lo - 0.001f * span - 1e-20f;
    S.sca[1] = hi + 0.001f * span + 1e-20f;
    S.sca[2] = 1.1754944e-38f * fmaxf(1.f, me2);
  }
  __syncthreads();
  const float pivmin = S.sca[2];

  // ---- 33-way multisection: 32 threads per eigenvalue, 8 rounds ----
  {
    const int grp = tid >> 5, gt = tid & 31;
    if (grp < RR) {
      const int krank = N - 1 - grp;
      float lo = S.sca[0], hi = S.sca[1];
      for (int round = 0; round < 8; ++round) {
        float w = (hi - lo) * (1.f / 33.f);
        float sg = fmaf(w, (float)(gt + 1), lo);
        int cnt = 0;
        float qq = S.dd[0] - sg;
        if (qq < 0.f) cnt++;
        for (int ii = 1; ii < N; ++ii) {
          if (fabsf(qq) < pivmin) qq = -pivmin;
          qq = S.dd[ii] - sg - S.e2s[ii] / qq;
          if (qq < 0.f) cnt++;
        }
        float nlo = (cnt <= krank) ? sg : lo;
        float nhi = (cnt >  krank) ? sg : hi;
#pragma unroll
        for (int off = 16; off > 0; off >>= 1) {
          nlo = fmaxf(nlo, __shfl_down(nlo, off, 32));
          nhi = fminf(nhi, __shfl_down(nhi, off, 32));
        }
        nlo = __shfl(nlo, 0, 32);
        nhi = __shfl(nhi, 0, 32);
        lo = fminf(nlo, nhi); hi = fmaxf(nlo, nhi);
      }
      if (gt == 0) S.lam[grp] = 0.5f * (lo + hi) * (1.f + (float)grp * 3e-7f);
    }
  }
  __syncthreads();

  // ---- inverse iteration, register-carried recurrence ----
  if (tid < RR) {
    const int j = tid;
    float* u0 = &S.slv[j][0];
    float* u1 = &S.slv[j][128];
    float* u2 = &S.slv[j][256];
    float* vv = &S.vt[j][0];
    const float lj = S.lam[j];
    for (int k = 0; k < N; ++k) vv[k] = 1.f;
    for (int itr = 0; itr < 3; ++itr) {
      float d = S.dd[0] - lj;
      float e = S.ee[0];
      float cv = vv[0];
      for (int i = 0; i < N - 1; ++i) {
        float bi = S.ee[i];
        float d1 = S.dd[i + 1] - lj;
        float e1 = (i + 1 < N - 1) ? S.ee[i + 1] : 0.f;
        float vnext = vv[i + 1];
        float ai = d, ci = e;
        if (fabsf(ai) >= fabsf(bi)) {
          if (fabsf(ai) < pivmin) ai = (ai >= 0.f ? pivmin : -pivmin);
          float m = bi / ai;
          u0[i] = ai; u1[i] = ci; u2[i] = 0.f;
          d = d1 - m * ci;
          e = e1;
          vv[i] = cv;
          cv = vnext - m * cv;
        } else {
          float m = ai / bi;
          u0[i] = bi; u1[i] = d1; u2[i] = e1;
          d = ci - m * d1;
          e = -m * e1;
          vv[i] = vnext;
          cv = cv - m * vnext;
        }
      }
      if (fabsf(d) < pivmin) d = (d >= 0.f ? pivmin : -pivmin);
      float vi2 = cv / d;
      vv[N - 1] = vi2;
      float vi1 = (vv[N - 2] - u1[N - 2] * vi2) / u0[N - 2];
      vv[N - 2] = vi1;
      for (int i = N - 3; i >= 0; --i) {
        float t = (vv[i] - u1[i] * vi1 - u2[i] * vi2) / u0[i];
        vv[i] = t;
        vi2 = vi1; vi1 = t;
      }
      float mx = 0.f;
      for (int k = 0; k < N; ++k) mx = fmaxf(mx, fabsf(vv[k]));
      float inv = 1.f / fmaxf(mx, 1e-30f);
      for (int k = 0; k < N; ++k) vv[k] *= inv;
    }
  }
  __syncthreads();

  // ---- MGS orthonormalization (block-parallel) ----
  for (int j = 0; j < RR; ++j) {
    for (int i2 = 0; i2 < j; ++i2) {
      float p_ = 0.f;
      { int k = tid; if (k < N) p_ = S.vt[i2][k] * S.vt[j][k]; }
      float dp = blkReduceSum(p_, S.red, tid);
      { int k = tid; if (k < N) S.vt[j][k] -= dp * S.vt[i2][k]; }
    }
    float p_ = 0.f;
    { int k = tid; if (k < N) p_ = S.vt[j][k] * S.vt[j][k]; }
    float nn = blkReduceSum(p_, S.red, tid);
    float inv = rsqrtf(fmaxf(nn, 1e-33f));
    { int k = tid; if (k < N) S.vt[j][k] *= inv; }
    __syncthreads();
  }

  // ---- back-transform: v = H_0 ... H_{N-3} v; u from ApkL * scl ----
  for (int vec = wv; vec < RR; vec += EIG_WAVES) {
    float* v = &S.vt[vec][0];
    for (int h = N - 3; h >= 0; --h) {
      const float sh = S.scls[h];
      float dp = 0.f;
      for (int k = lane; k < N; k += 64) {
        float uk = (k <= h) ? 0.f : ((k == h + 1) ? 1.f : S.ApkL[((k * (k - 1)) >> 1) + h] * sh);
        dp += uk * v[k];
      }
#pragma unroll
      for (int off = 32; off > 0; off >>= 1) dp += __shfl_down(dp, off, 64);
      dp = __shfl(dp, 0, 64);
      float c = S.taus[h] * dp;
      for (int k = lane; k < N; k += 64) {
        float uk = (k <= h) ? 0.f : ((k == h + 1) ? 1.f : S.ApkL[((k * (k - 1)) >> 1) + h] * sh);
        v[k] -= c * uk;
      }
    }
  }
  __syncthreads();

  // ---- canonical sign (max-|component| positive) + write F (N x RR) ----
  for (int vec = wv; vec < RR; vec += EIG_WAVES) {
    float* v = &S.vt[vec][0];
    float ma = -1.f; int mi = 0x7fffffff;
    for (int k = lane; k < N; k += 64) {
      float a = fabsf(v[k]);
      if (a > ma || (a == ma && k < mi)) { ma = a; mi = k; }
    }
#pragma unroll
    for (int off = 32; off > 0; off >>= 1) {
      float oa = __shfl_down(ma, off, 64);
      int oi = __shfl_down(mi, off, 64);
      if (oa > ma || (oa == ma && oi < mi)) { ma = oa; mi = oi; }
    }
    mi = __shfl(mi, 0, 64);
    float sg = (v[mi] < 0.f) ? -1.f : 1.f;
    for (int k = lane; k < N; k += 64) F[k * RR + vec] = sg * v[k];
  }
}

__global__ __launch_bounds__(EIG_THREADS, 1)
void keigh_init(const float* G0, float* F0, const float* G1, float* F1,
                const float* G2, float* F2, const float* G3, float* F3) {
  __shared__ ESm S;
  if (blockIdx.x == 0)      eig_body<32, 8>(S, G0, F0);
  else if (blockIdx.x == 1) eig_body<100, 6>(S, G1, F1);
  else if (blockIdx.x == 2) eig_body<128, 6>(S, G2, F2);
  else                      eig_body<64, 6>(S, G3, F3);
}

template<int N, int RR>
__global__ __launch_bounds__(EIG_THREADS, 1)
void keigh_one(const float* __restrict__ G, float* __restrict__ F) {
  __shared__ ESm S;
  eig_body<N, RR>(S, G, F);
}

// ---------------------------------------------------------------------------
extern "C" void kernel_launch(void* const* d_in, const int* in_sizes, int n_in,
                              void* d_out, int out_size, void* d_ws, size_t ws_size,
                              hipStream_t stream) {
  (void)in_sizes; (void)n_in; (void)out_size; (void)ws_size;
  const float* x  = (const float*)d_in[0];
  const float* cw = (const float*)d_in[1];
  const float* cb = (const float*)d_in[2];
  float* out = (float*)d_out;
  float* ws  = (float*)d_ws;

  float* T    = ws + OFF_T;
  float* TC   = ws + OFF_TC;
  float* TB   = ws + OFF_TB;
  float* PART = ws + OFF_PART;
  float* TD0a = ws + OFF_TD0a;
  float* TD0b = ws + OFF_TD0b;
  float* TD   = ws + OFF_TD;
  float* G0   = ws + OFF_G0;
  float* G1   = ws + OFF_G1;
  float* G2   = ws + OFF_G2;
  float* G3   = ws + OFF_G3;
  float* F0   = ws + OFF_F0;
  float* F1   = ws + OFF_F1;
  float* F2   = ws + OFF_F2;
  float* F3   = ws + OFF_F3;

  kconv<<<(26214400 + 255) / 256, 256, 0, stream>>>(x, cw, cb, T);

  // ---- HOSVD init: 4 grams, then one batched 4-block eigh ----
  kgram_big<32, 819200, false><<<GRAM_BLOCKS, 256, 0, stream>>>(T, PART, 1);
  kreduce<<<4, 256, 0, stream>>>(PART, G0, 1024);
  kgram_big<100, 8192, false><<<GRAM_BLOCKS, 256, 0, stream>>>(T, PART, 32);
  kreduce<<<40, 256, 0, stream>>>(PART, G1, 10000);
  kgram_big<128, 64, false><<<GRAM_BLOCKS, 256, 0, stream>>>(T, PART, 3200);
  kreduce<<<64, 256, 0, stream>>>(PART, G2, 16384);
  kgram_big<64, 1, true><<<GRAM_BLOCKS, 256, 0, stream>>>(T, PART, 409600);
  kreduce<<<16, 256, 0, stream>>>(PART, G3, 4096);

  keigh_init<<<4, EIG_THREADS, 0, stream>>>(G0, F0, G1, F1, G2, F2, G3, F3);

  // ---- HOOI sweeps ----
  for (int sweep = 0; sweep < 5; ++sweep) {
    // mode 0: Y = T x1 F1 x2 F2 x3 F3 -> (32,6,6,6)
    kcontract<6, 8192><<<1024, 256, 0, stream>>>(T, F1, TB, 32, 100);
    kcontract<6, 64><<<48, 256, 0, stream>>>(TB, F2, TD0a, 192, 128);
    kcontract<6, 1><<<5, 256, 0, stream>>>(TD0a, F3, TD0b, 1152, 64);
    kgram_small<<<4, 256, 0, stream>>>(TD0b, G0, 1, 32, 216);
    keigh_one<32, 8><<<1, EIG_THREADS, 0, stream>>>(G0, F0);
    // TC = T x0 F0 (reused by modes 1,2,3 and the final core)
    kcontract<8, 819200><<<3200, 256, 0, stream>>>(T, F0, TC, 1, 32);
    // mode 1
    kcontract<6, 64><<<200, 256, 0, stream>>>(TC, F2, TB, 800, 128);
    kcontract<6, 1><<<19, 256, 0, stream>>>(TB, F3, TD, 4800, 64);
    kgram_small<<<40, 256, 0, stream>>>(TD, G0, 8, 100, 36);
    keigh_one<100, 6><<<1, EIG_THREADS, 0, stream>>>(G0, F1);
    // mode 2 (TB = TC x1 F1 also reused by mode 3)
    kcontract<6, 8192><<<256, 256, 0, stream>>>(TC, F1, TB, 8, 100);
    kcontract<6, 1><<<24, 256, 0, stream>>>(TB, F3, TD, 6144, 64);
    kgram_small<<<64, 256, 0, stream>>>(TD, G0, 48, 128, 6);
    keigh_one<128, 6><<<1, EIG_THREADS, 0, stream>>>(G0, F2);
    // mode 3 (reuses TB from mode 2)
    kcontract<6, 64><<<12, 256, 0, stream>>>(TB, F2, TD, 48, 128);
    kgram_small<<<16, 256, 0, stream>>>(TD, G0, 288, 64, 1);
    keigh_one<64, 6><<<1, EIG_THREADS, 0, stream>>>(G0, F3);
  }

  // ---- core = (TC) x1 F1 x2 F2 x3 F3 -> (8,6,6,6) ----
  kcontract<6, 8192><<<256, 256, 0, stream>>>(TC, F1, TB, 8, 100);
  kcontract<6, 64><<<12, 256, 0, stream>>>(TB, F2, TD, 48, 128);
  kcontract<6, 1><<<2, 256, 0, stream>>>(TD, F3, out, 288, 64);
}